// Round 1
// 91.029 us; speedup vs baseline: 1.1361x; 1.1361x over previous
//
#include <hip/hip_runtime.h>
#include <hip/hip_fp16.h>
#include <math.h>

#define NPTS 17
#define DCH 128
#define HF 56
#define WF 100

using half8 = __attribute__((ext_vector_type(8))) _Float16;
using f32x4 = __attribute__((ext_vector_type(4))) float;

// ---- workspace layout (float offsets) ----
#define OFF_WKB   0          // 128 f32: q_W @ k_b
#define OFF_A0    24576      // 128
#define OFF_B0    24704      // 128
#define OFF_C0    24832      // 1
#define OFF_W2T   24836      // 128*128 f16: w2t[c][k] = sum_e qW[k][e] kW[c][e]
#define OFF_BMT   33028      // 128*128 f16: BmT[d][i]
#define OFF_FEAT  41220      // 2*56*100*128 f16
#define OFF_Q     758020     // 40000*128 f16 (valid rows only: q, then PRE)
#define OFF_LRN   3318020    // 40000*34 f32
#define OFF_CK    4678020    // 40000
#define OFF_SATTN 4718020    // 40000
#define OFF_IDX   4758020    // 40000 ints (compacted: [valid... | skip...])
#define OFF_CNT   4798020    // 2 ints (memset to 0 each launch)

__device__ inline __half2 bc_h2(unsigned u) { return __builtin_bit_cast(__half2, u); }
__device__ inline unsigned bc_u32(__half2 h) { return __builtin_bit_cast(unsigned, h); }
__device__ inline unsigned packh2(float a, float b) {
  return bc_u32(__float22half2_rn(make_float2(a, b)));
}
__device__ inline ushort f2hu(float x) {
  __half h = __float2half(x);
  return __builtin_bit_cast(ushort, h);
}

__device__ inline int swz(int row, int bcol) {        // 256B rows
  return (row << 8) + (bcol ^ ((row & 7) << 4));
}
__device__ inline int swz7(int row, int bcol) {       // 128B rows
  return (row << 7) + (bcol ^ ((row & 7) << 4));
}

// shared projection: (u_n, v_n) for point n
__device__ inline void project(int4 iv, const float* voxel_size,
    const float* pc_range, const float* trans, float winv, float hinv,
    float& u_n, float& v_n, int& bidx)
{
  bidx = iv.x;
  float cv0 = voxel_size[0]*8.f, cv1 = voxel_size[1]*8.f, cv2 = voxel_size[2]*8.f;
  float ph0 = (float)iv.w*cv0 + pc_range[0] + 0.5f*cv0;
  float ph1 = (float)iv.z*cv1 + pc_range[1] + 0.5f*cv1;
  float ph2 = (float)iv.y*cv2 + pc_range[2] + 0.5f*cv2;
  const float* T = trans + bidx*12;
  float p0 = T[0]*ph0 + T[1]*ph1 + T[2]*ph2  + T[3];
  float p1 = T[4]*ph0 + T[5]*ph1 + T[6]*ph2  + T[7];
  float p2 = T[8]*ph0 + T[9]*ph1 + T[10]*ph2 + T[11];
  float depth = fmaxf(p2, 1e-5f);
  u_n = 2.f*((p0/depth)*winv/99.f) - 1.f;
  v_n = 2.f*((p1/depth)*hinv/55.f) - 1.f;
}

// One launch: [0,112) feat conversion | [112,112+nbc) compact |
// +0: w2t MFMA | +1..+64: bmt serial | +65: aux vectors.
__global__ __launch_bounds__(256) void fused_prep_kernel(
    const float* __restrict__ img,
    const float* __restrict__ q_W, const float* __restrict__ k_W,
    const float* __restrict__ v_W, const float* __restrict__ out_W,
    const float* __restrict__ q_b, const float* __restrict__ k_b,
    const float* __restrict__ v_b,
    const int* __restrict__ indices,
    const float* __restrict__ voxel_size, const float* __restrict__ pc_range,
    const float* __restrict__ trans,
    const int* __restrict__ HimgP, const int* __restrict__ WimgP,
    float* __restrict__ ws, int N, int nbc)
{
  __shared__ __align__(16) char smraw[DCH*101*4];
  int tid = threadIdx.x;
  int bid = blockIdx.x;

  if (bid < 112) {
    // ---- img feats -> channel-last f16 ----
    float* sm = (float*)smraw;
    int b = bid / HF, y = bid % HF;
    const float* src = img + (size_t)b*DCH*HF*WF + y*WF;
    #pragma unroll
    for (int i = 0; i < 50; ++i) {
      int flat = i*256 + tid;
      int c = flat / WF;
      int x = flat - c*WF;
      sm[c*101 + x] = src[(size_t)c*HF*WF + x];
    }
    __syncthreads();
    unsigned* dst = (unsigned*)((ushort*)(ws + OFF_FEAT) + (size_t)(b*HF*WF + y*WF)*DCH);
    #pragma unroll
    for (int i = 0; i < 25; ++i) {
      int flat = i*256 + tid;
      int x = flat >> 6;
      int cp = flat & 63;
      dst[(size_t)x*64 + cp] = packh2(sm[(2*cp)*101 + x], sm[(2*cp+1)*101 + x]);
    }
    return;
  }
  bid -= 112;

  if (bid < nbc) {
    // ---- compaction (counters pre-zeroed by memset) ----
    int n = bid * 256 + tid;
    if (n >= N) return;
    const float du = 2.0f/99.0f, dv = 2.0f/55.0f;
    float winv = (float)WF / (float)(WimgP[0]);
    float hinv = (float)HF / (float)(HimgP[0]);
    float u_n, v_n; int bx;
    project(((const int4*)indices)[n], voxel_size, pc_range, trans, winv, hinv,
            u_n, v_n, bx);
    bool cskip = (fabsf(u_n) > 1.001f + 4.5f*du) || (fabsf(v_n) > 1.001f + 4.5f*dv);
    int* cnt = (int*)(ws + OFF_CNT);
    int* idx = (int*)(ws + OFF_IDX);
    if (!cskip) {
      int s = atomicAdd(&cnt[0], 1);
      idx[s] = n;
    } else {
      int s = atomicAdd(&cnt[1], 1);
      idx[N - 1 - s] = n;
    }
    return;
  }
  bid -= nbc;

  if (bid == 0) {
    // ---- w2t[t][j] = sum_e kW[t][e] qW[j][e]  (MFMA, A=kW rows, B=qW rows) ----
    char* Als = smraw;            // 128 rows x 64 f16 (128B rows)
    char* Bls = smraw + 16384;
    ushort* w2t = (ushort*)(ws + OFF_W2T);
    int wid = tid >> 6, l = tid & 63, lr = l & 15, lg = l >> 4;
    f32x4 acc[2][8] = {};
    for (int ko = 0; ko < 2; ++ko) {
      __syncthreads();
      #pragma unroll
      for (int i = 0; i < 16; ++i) {
        int flat = i*256 + tid;           // 4096 pairs per matrix
        int r = flat >> 5, kp = flat & 31;
        float2 va = *(const float2*)&k_W[r*DCH + ko*64 + 2*kp];
        float2 vb = *(const float2*)&q_W[r*DCH + ko*64 + 2*kp];
        *(unsigned*)(Als + swz7(r, kp*4)) = packh2(va.x, va.y);
        *(unsigned*)(Bls + swz7(r, kp*4)) = packh2(vb.x, vb.y);
      }
      __syncthreads();
      #pragma unroll
      for (int kc = 0; kc < 2; ++kc) {
        int kb = kc*64 + lg*16;
        half8 a0 = *(const half8*)(Als + swz7(wid*32 + lr, kb));
        half8 a1 = *(const half8*)(Als + swz7(wid*32 + 16 + lr, kb));
        #pragma unroll
        for (int ni = 0; ni < 8; ++ni) {
          half8 b = *(const half8*)(Bls + swz7(ni*16 + lr, kb));
          acc[0][ni] = __builtin_amdgcn_mfma_f32_16x16x32_f16(a0, b, acc[0][ni], 0, 0, 0);
          acc[1][ni] = __builtin_amdgcn_mfma_f32_16x16x32_f16(a1, b, acc[1][ni], 0, 0, 0);
        }
      }
    }
    #pragma unroll
    for (int mi = 0; mi < 2; ++mi) {
      #pragma unroll
      for (int reg = 0; reg < 4; ++reg) {
        int n = wid*32 + mi*16 + lg*4 + reg;
        #pragma unroll
        for (int ni = 0; ni < 8; ++ni)
          w2t[n*DCH + ni*16 + lr] = f2hu(acc[mi][ni][reg]);
      }
    }
    return;
  }
  bid -= 1;

  if (bid < 64) {
    // ---- BmT[d][i] = sum_e vW[i][e] outW[e][d]  (serial, 2 rows/block) ----
    float* smv = (float*)smraw;          // [2][128]
    int half = tid >> 7, t = tid & 127;
    int i2 = bid*2 + half;
    smv[half*128 + t] = v_W[(size_t)i2*DCH + t];
    __syncthreads();
    const float* row = smv + half*128;
    float acc = 0.f;
    for (int e = 0; e < DCH; ++e) acc += row[e] * out_W[(size_t)e*DCH + t];
    ((ushort*)(ws + OFF_BMT))[t*DCH + i2] = f2hu(acc);
    return;
  }

  // ---- aux vectors ----
  if (tid < DCH) {
    int t = tid;
    float a0 = 0.f, b0 = 0.f, wkb = 0.f;
    for (int e = 0; e < DCH; ++e) {
      a0  += k_W[(size_t)t*DCH + e] * q_b[e];
      b0  += v_b[e] * out_W[(size_t)e*DCH + t];
      wkb += q_W[(size_t)t*DCH + e] * k_b[e];
    }
    ws[OFF_A0 + t]  = a0;
    ws[OFF_B0 + t]  = b0;
    ws[OFF_WKB + t] = wkb;
    if (t == 0) {
      float c0 = 0.f;
      for (int e = 0; e < DCH; ++e) c0 += q_b[e] * k_b[e];
      ws[OFF_C0] = c0;
    }
  }
}

// y==0: valid-only q-GEMM (gather rows via idx, 64x128 per block, scatter Qh).
// y==1: fp32 ofs path for ALL rows (offset_W read directly; col 34 = wkb -> CK).
__global__ __launch_bounds__(256) void qgemm_kernel(
    const float* __restrict__ X, const float* __restrict__ offset_W,
    const float* __restrict__ offset_b,
    float* __restrict__ ws, int N)
{
  __shared__ __align__(16) char u[49152];
  int tid = threadIdx.x;
  int n0 = blockIdx.x * 64;

  if (blockIdx.y == 1) {
    // ---- ofs: fp32 GEMM for LRN(34)+CK(1) ----
    float* XsT = (float*)u;              // [64][68]
    float* Ws  = (float*)(u + 17408);    // [64][36]
    float acc[4][4] = {};
    int tr = (tid & 15) << 2;
    int tc = (tid >> 4) << 2;
    for (int kc = 0; kc < 2; ++kc) {
      __syncthreads();
      #pragma unroll
      for (int i = 0; i < 16; ++i) {
        int flat = i*256 + tid;
        int r = flat >> 6, k = flat & 63;
        int rr = n0 + r; if (rr >= N) rr = N - 1;
        XsT[k*68 + r] = X[(size_t)rr*DCH + kc*64 + k];
      }
      #pragma unroll
      for (int i = 0; i < 9; ++i) {
        int flat = i*256 + tid;
        if (flat < 2304) {
          int k = flat / 36, c = flat - k*36;
          float val;
          if (c < 34)       val = offset_W[(size_t)(kc*64 + k)*34 + c];
          else if (c == 34) val = ws[OFF_WKB + kc*64 + k];
          else              val = 0.f;
          Ws[k*36 + c] = val;
        }
      }
      __syncthreads();
      #pragma unroll 8
      for (int k = 0; k < 64; ++k) {
        float4 a = *(const float4*)&XsT[k*68 + tr];
        float4 b = *(const float4*)&Ws[k*36 + tc];
        acc[0][0] += a.x*b.x; acc[0][1] += a.x*b.y; acc[0][2] += a.x*b.z; acc[0][3] += a.x*b.w;
        acc[1][0] += a.y*b.x; acc[1][1] += a.y*b.y; acc[1][2] += a.y*b.z; acc[1][3] += a.y*b.w;
        acc[2][0] += a.z*b.x; acc[2][1] += a.z*b.y; acc[2][2] += a.z*b.z; acc[2][3] += a.z*b.w;
        acc[3][0] += a.w*b.x; acc[3][1] += a.w*b.y; acc[3][2] += a.w*b.z; acc[3][3] += a.w*b.w;
      }
    }
    const float du = 2.0f/99.0f, dv = 2.0f/55.0f;
    #pragma unroll
    for (int i = 0; i < 4; ++i) {
      int n = n0 + tr + i;
      if (n >= N) continue;
      #pragma unroll
      for (int j = 0; j < 4; ++j) {
        int o = tc + j;
        float v = acc[i][j];
        if (o < 34) {
          float sc = (o & 1) ? 1.5f*dv : 1.5f*du;
          ws[OFF_LRN + (size_t)n*34 + o] = tanhf(v + offset_b[o]) * sc;
        } else if (o == 34) {
          ws[OFF_CK + n] = v + ws[OFF_C0];
        }
      }
    }
    return;
  }

  // ---- y==0: valid-only q-GEMM ----
  int nvalid = ((const int*)(ws + OFF_CNT))[0];
  if (n0 >= nvalid) return;
  const int* idxp = (const int*)(ws + OFF_IDX);
  char* Als = u;            // 64 x 256B
  char* Bls = u + 16384;    // 128 x 256B
  const ushort* Wt = (const ushort*)(ws + OFF_W2T);

  #pragma unroll
  for (int i = 0; i < 8; ++i) {
    int flat = i*1024 + tid*4;
    int r = flat >> 7, k = flat & 127;
    int sl = n0 + r; if (sl >= nvalid) sl = nvalid - 1;
    int pt = idxp[sl];
    float4 v = *(const float4*)&X[(size_t)pt*DCH + k];
    uint2 pkv;
    pkv.x = packh2(v.x, v.y);
    pkv.y = packh2(v.z, v.w);
    *(uint2*)(Als + swz(r, k*2)) = pkv;
  }
  #pragma unroll
  for (int i = 0; i < 8; ++i) {
    int flat = i*2048 + tid*8;
    int r = flat >> 7, k = flat & 127;
    *(uint4*)(Bls + swz(r, k*2)) = *(const uint4*)&Wt[(size_t)r*DCH + k];
  }
  __syncthreads();

  int wid = tid >> 6;
  int wr = wid >> 1, wc = wid & 1;
  int l = tid & 63, lr = l & 15, lg = l >> 4;

  f32x4 acc[2][4] = {};
  #pragma unroll
  for (int kc = 0; kc < 4; ++kc) {
    int kb = kc*64 + lg*16;
    half8 a0 = *(const half8*)(Als + swz(wr*32 + lr, kb));
    half8 a1 = *(const half8*)(Als + swz(wr*32 + 16 + lr, kb));
    #pragma unroll
    for (int ni = 0; ni < 4; ++ni) {
      half8 b = *(const half8*)(Bls + swz(wc*64 + ni*16 + lr, kb));
      acc[0][ni] = __builtin_amdgcn_mfma_f32_16x16x32_f16(a0, b, acc[0][ni], 0, 0, 0);
      acc[1][ni] = __builtin_amdgcn_mfma_f32_16x16x32_f16(a1, b, acc[1][ni], 0, 0, 0);
    }
  }

  ushort* Qh = (ushort*)(ws + OFF_Q);
  #pragma unroll
  for (int mi = 0; mi < 2; ++mi) {
    #pragma unroll
    for (int reg = 0; reg < 4; ++reg) {
      int slot = n0 + wr*32 + mi*16 + lg*4 + reg;
      if (slot >= nvalid) continue;
      int pt = idxp[slot];
      #pragma unroll
      for (int ni = 0; ni < 4; ++ni) {
        int c = wc*64 + ni*16 + lr;
        Qh[(size_t)pt*DCH + c] = f2hu(acc[mi][ni][reg] + ws[OFF_A0 + c]);
      }
    }
  }
}

// 4 pts/wave via compacted idx. Slots < nvalid: dense slow path.
// Slots >= nvalid: provably-invalid, stats only (no Qh/SATTN writes needed).
__global__ __launch_bounds__(256) void sample_kernel(
    const int* __restrict__ indices,
    const float* __restrict__ voxel_size, const float* __restrict__ pc_range,
    const float* __restrict__ trans,
    float* __restrict__ ws,
    const int* __restrict__ HimgP, const int* __restrict__ WimgP,
    float* __restrict__ out, int N)
{
  int tid  = threadIdx.x;
  int wave = tid >> 6;
  int lane = tid & 63;
  int g    = lane >> 4;
  int mm   = lane & 15;
  int slot = blockIdx.x * 16 + wave * 4 + g;
  bool active = (slot < N);
  int sl = active ? slot : (N - 1);

  const int* idx = (const int*)(ws + OFF_IDX);
  int nvalid = ((const int*)(ws + OFF_CNT))[0];
  int pt = idx[sl];

  ushort* Qh = (ushort*)(ws + OFF_Q);
  const char* fb = (const char*)(ws + OFF_FEAT);
  const float* LRN = ws + OFF_LRN + (size_t)pt*34;
  const float du = 2.0f/99.0f, dv = 2.0f/55.0f;

  if (sl >= nvalid) {
    // ---- fast path: all 17 points provably invalid ----
    float instab = 0.f;
    #pragma unroll
    for (int p = 0; p < NPTS; ++p) {
      float2 lr = *(const float2*)&LRN[2*p];
      instab += sqrtf(lr.x*lr.x + lr.y*lr.y);
    }
    if (active && mm == 0) {
      out[(size_t)N*128 + pt] = 0.f;
      float osc = 1.5f * sqrtf(du*du + dv*dv);
      float inst = (instab / 17.f) / fmaxf(osc, 1e-6f);
      out[(size_t)N*129 + pt] = fminf(fmaxf(__expf(-inst), 0.f), 1.f);
      float ent = 17.f * 1.3815511e-5f;
      out[(size_t)N*130 + pt] = fminf(fmaxf(1.f - ent / logf(17.f), 0.f), 1.f);
    }
    return;
  }

  // ---- slow path (dense valid-candidate points) ----
  float winv = (float)WF / (float)(WimgP[0]);
  float hinv = (float)HF / (float)(HimgP[0]);
  float u_n, v_n; int bidx;
  project(((const int4*)indices)[pt], voxel_size, pc_range, trans, winv, hinv,
          u_n, v_n, bidx);

  uint4 qp = *(const uint4*)&Qh[(size_t)pt*DCH + 8*mm];
  __half2 q01 = bc_h2(qp.x), q23 = bc_h2(qp.y), q45 = bc_h2(qp.z), q67 = bc_h2(qp.w);
  float ck = ws[OFF_CK + pt];

  const float BOX[NPTS] = {-1,-1,-1, 0,0,0, 1,1,1, -3,-3,-3, 0,0, 3,3,3};
  const float BOY[NPTS] = {-1, 0, 1,-1,0,1,-1,0,1, -3, 0, 3, -3,3,-3,0,3};
  const float scale = 0.17677669529663689f;  // 32^-0.5

  float larr[NPTS];
  unsigned vm = 0;
  float instab = 0.f;
  float m_run = -1e28f, srun = 0.f;
  __half2 pre01 = __float2half2_rn(0.f), pre23 = __float2half2_rn(0.f);
  __half2 pre45 = __float2half2_rn(0.f), pre67 = __float2half2_rn(0.f);
  int fbase = bidx * (HF*WF);
  int moff = mm * 16;

  #pragma unroll
  for (int p = 0; p < NPTS; ++p) {
    float2 lr = *(const float2*)&LRN[2*p];
    instab += sqrtf(lr.x*lr.x + lr.y*lr.y);
    float gx = u_n + BOX[p]*du + lr.x;
    float gy = v_n + BOY[p]*dv + lr.y;
    bool valid = (fabsf(gx) <= 1.f) && (fabsf(gy) <= 1.f);
    float l = -1e30f;
    if (valid) {
      vm |= (1u << p);
      float px = fmaf(gx, 49.5f, 49.5f);
      float py = fmaf(gy, 27.5f, 27.5f);
      float fpx = floorf(px), fpy = floorf(py);
      float fx = px - fpx, fy = py - fpy;
      int x0 = (int)fpx, y0 = (int)fpy;
      int x1 = min(x0 + 1, WF - 1), y1 = min(y0 + 1, HF - 1);
      float wy0 = 1.f - fy, wx0 = 1.f - fx;
      __half2 h00 = __float2half2_rn(wy0*wx0);
      __half2 h01 = __float2half2_rn(wy0*fx);
      __half2 h10 = __float2half2_rn(fy*wx0);
      __half2 h11 = __float2half2_rn(fy*fx);
      int r0 = (fbase + y0*WF) << 8, r1 = (fbase + y1*WF) << 8;
      uint4 f00 = *(const uint4*)(fb + r0 + (x0 << 8) + moff);
      uint4 f01 = *(const uint4*)(fb + r0 + (x1 << 8) + moff);
      uint4 f10 = *(const uint4*)(fb + r1 + (x0 << 8) + moff);
      uint4 f11 = *(const uint4*)(fb + r1 + (x1 << 8) + moff);
      __half2 s01 = __hfma2(h00, bc_h2(f00.x),
                    __hfma2(h01, bc_h2(f01.x),
                    __hfma2(h10, bc_h2(f10.x),
                    __hmul2(h11, bc_h2(f11.x)))));
      __half2 s23 = __hfma2(h00, bc_h2(f00.y),
                    __hfma2(h01, bc_h2(f01.y),
                    __hfma2(h10, bc_h2(f10.y),
                    __hmul2(h11, bc_h2(f11.y)))));
      __half2 s45 = __hfma2(h00, bc_h2(f00.z),
                    __hfma2(h01, bc_h2(f01.z),
                    __hfma2(h10, bc_h2(f10.z),
                    __hmul2(h11, bc_h2(f11.z)))));
      __half2 s67 = __hfma2(h00, bc_h2(f00.w),
                    __hfma2(h01, bc_h2(f01.w),
                    __hfma2(h10, bc_h2(f10.w),
                    __hmul2(h11, bc_h2(f11.w)))));
      __half2 dh = __hfma2(s01, q01, __hfma2(s23, q23,
                   __hfma2(s45, q45, __hmul2(s67, q67))));
      float part = __low2float(dh) + __high2float(dh);
      part += __shfl_xor(part, 8);
      part += __shfl_xor(part, 4);
      part += __shfl_xor(part, 2);
      part += __shfl_xor(part, 1);
      l = (part + ck) * scale;
      float nm  = fmaxf(m_run, l);
      float esc = __expf(m_run - nm);
      float a   = __expf(l - nm);
      m_run = nm;
      srun = srun*esc + a;
      __half2 esch = __float2half2_rn(esc);
      __half2 ah   = __float2half2_rn(a);
      pre01 = __hfma2(ah, s01, __hmul2(pre01, esch));
      pre23 = __hfma2(ah, s23, __hmul2(pre23, esch));
      pre45 = __hfma2(ah, s45, __hmul2(pre45, esch));
      pre67 = __hfma2(ah, s67, __hmul2(pre67, esch));
    }
    larr[p] = l;
  }

  bool anyv = (vm != 0);
  float off  = anyv ? (m_run + __logf(srun)) : 1e38f;
  float invs = anyv ? 1.f/srun : 0.f;
  __half2 ih = __float2half2_rn(invs);
  pre01 = __hmul2(pre01, ih);
  pre23 = __hmul2(pre23, ih);
  pre45 = __hmul2(pre45, ih);
  pre67 = __hmul2(pre67, ih);

  float ent = 0.f;
  #pragma unroll
  for (int p = 0; p < NPTS; ++p) {
    float d = off - larr[p];
    float a = __expf(-d);
    ent += (a >= 1e-6f) ? a*d : 1.3815511e-5f;
  }

  if (active) {
    uint4 pw;
    pw.x = bc_u32(pre01);
    pw.y = bc_u32(pre23);
    pw.z = bc_u32(pre45);
    pw.w = bc_u32(pre67);
    *(uint4*)&Qh[(size_t)pt*DCH + 8*mm] = pw;
    if (mm == 0) {
      ws[OFF_SATTN + pt] = anyv ? 1.f : 0.f;
      out[(size_t)N*128 + pt] = (float)__popc(vm) / 17.f;
      float osc = 1.5f * sqrtf(du*du + dv*dv);
      float inst = (instab / 17.f) / fmaxf(osc, 1e-6f);
      out[(size_t)N*129 + pt] = fminf(fmaxf(__expf(-inst), 0.f), 1.f);
      out[(size_t)N*130 + pt] = fminf(fmaxf(1.f - ent / logf(17.f), 0.f), 1.f);
    }
  }
}

// Out GEMM: MFMA only for valid slots (gather PRE, scatter out);
// invalid slots get out[pt] = out_b (fill, no reads).
__global__ __launch_bounds__(256) void ogemm_kernel(
    float* __restrict__ ws, const float* __restrict__ out_b,
    float* __restrict__ out, int N)
{
  __shared__ __align__(16) char u[32768];
  int tid = threadIdx.x;
  int n0 = blockIdx.x * 64;
  int c0 = blockIdx.y * 64;
  int nvalid = ((const int*)(ws + OFF_CNT))[0];
  const int* idxp = (const int*)(ws + OFF_IDX);

  if (n0 + 64 > nvalid) {
    // fill slots in [max(n0,nvalid), min(n0+64,N))
    int r = tid >> 2, q = tid & 3;
    int slot = n0 + r;
    if (slot >= nvalid && slot < N) {
      int pt = idxp[slot];
      float* dst = out + (size_t)pt*DCH + c0 + q*16;
      const float* src = out_b + c0 + q*16;
      #pragma unroll
      for (int j = 0; j < 4; ++j)
        *(float4*)(dst + 4*j) = *(const float4*)(src + 4*j);
    }
    if (n0 >= nvalid) return;
  }

  char* Als = u;
  char* Bls = u + 16384;
  const ushort* Xh = (const ushort*)(ws + OFF_Q);
  const ushort* Wt = (const ushort*)(ws + OFF_BMT);

  #pragma unroll
  for (int i = 0; i < 4; ++i) {
    int flat = i*2048 + tid*8;
    int r = flat >> 7, k = flat & 127;
    int sl = n0 + r; if (sl >= nvalid) sl = nvalid - 1;
    int pt = idxp[sl];
    *(uint4*)(Als + swz(r, k*2)) = *(const uint4*)&Xh[(size_t)pt*DCH + k];
  }
  #pragma unroll
  for (int i = 0; i < 4; ++i) {
    int flat = i*2048 + tid*8;
    int r = flat >> 7, k = flat & 127;
    *(uint4*)(Bls + swz(r, k*2)) = *(const uint4*)&Wt[(size_t)(c0 + r)*DCH + k];
  }
  __syncthreads();

  int wid = tid >> 6;
  int wr = wid >> 1, wc = wid & 1;
  int l = tid & 63, lr = l & 15, lg = l >> 4;

  f32x4 acc[2][2] = {};
  #pragma unroll
  for (int kc = 0; kc < 4; ++kc) {
    int kb = kc*64 + lg*16;
    half8 a0 = *(const half8*)(Als + swz(wr*32 + lr, kb));
    half8 a1 = *(const half8*)(Als + swz(wr*32 + 16 + lr, kb));
    half8 b0 = *(const half8*)(Bls + swz(wc*32 + lr, kb));
    half8 b1 = *(const half8*)(Bls + swz(wc*32 + 16 + lr, kb));
    acc[0][0] = __builtin_amdgcn_mfma_f32_16x16x32_f16(a0, b0, acc[0][0], 0, 0, 0);
    acc[0][1] = __builtin_amdgcn_mfma_f32_16x16x32_f16(a0, b1, acc[0][1], 0, 0, 0);
    acc[1][0] = __builtin_amdgcn_mfma_f32_16x16x32_f16(a1, b0, acc[1][0], 0, 0, 0);
    acc[1][1] = __builtin_amdgcn_mfma_f32_16x16x32_f16(a1, b1, acc[1][1], 0, 0, 0);
  }

  #pragma unroll
  for (int mi = 0; mi < 2; ++mi) {
    #pragma unroll
    for (int reg = 0; reg < 4; ++reg) {
      int slot = n0 + wr*32 + mi*16 + lg*4 + reg;
      if (slot >= nvalid) continue;
      int pt = idxp[slot];
      float sa = ws[OFF_SATTN + pt];
      #pragma unroll
      for (int ni = 0; ni < 2; ++ni) {
        int c = c0 + wc*32 + ni*16 + lr;
        out[(size_t)pt*DCH + c] = acc[mi][ni][reg] + sa*ws[OFF_B0 + c] + out_b[c];
      }
    }
  }
}

extern "C" void kernel_launch(void* const* d_in, const int* in_sizes, int n_in,
                              void* d_out, int out_size, void* d_ws, size_t ws_size,
                              hipStream_t stream) {
  const float* x_lidar    = (const float*)d_in[0];
  const int*   indices    = (const int*)  d_in[1];
  const float* img        = (const float*)d_in[2];
  const float* voxel_size = (const float*)d_in[3];
  const float* pc_range   = (const float*)d_in[4];
  const float* trans      = (const float*)d_in[5];
  const float* offset_W   = (const float*)d_in[6];
  const float* offset_b   = (const float*)d_in[7];
  const float* q_W        = (const float*)d_in[8];
  const float* q_b        = (const float*)d_in[9];
  const float* k_W        = (const float*)d_in[10];
  const float* k_b        = (const float*)d_in[11];
  const float* v_W        = (const float*)d_in[12];
  const float* v_b        = (const float*)d_in[13];
  const float* out_W      = (const float*)d_in[14];
  const float* out_b      = (const float*)d_in[15];
  const int*   Himg       = (const int*)  d_in[16];
  const int*   Wimg       = (const int*)  d_in[17];
  float* ws  = (float*)d_ws;
  float* out = (float*)d_out;
  int N = in_sizes[0] / DCH;
  int rt  = (N + 63) / 64;
  int nbc = (N + 255) / 256;

  hipMemsetAsync(ws + OFF_CNT, 0, 2*sizeof(int), stream);
  hipLaunchKernelGGL(fused_prep_kernel, dim3(112 + nbc + 66), dim3(256), 0, stream,
                     img, q_W, k_W, v_W, out_W, q_b, k_b, v_b,
                     indices, voxel_size, pc_range, trans, Himg, Wimg, ws, N, nbc);
  hipLaunchKernelGGL(qgemm_kernel, dim3(rt, 2), dim3(256), 0, stream,
                     x_lidar, offset_W, offset_b, ws, N);
  hipLaunchKernelGGL(sample_kernel, dim3((N + 15) / 16), dim3(256), 0, stream,
                     indices, voxel_size, pc_range, trans, ws, Himg, Wimg, out, N);
  hipLaunchKernelGGL(ogemm_kernel, dim3(rt, 2), dim3(256), 0, stream,
                     ws, out_b, out, N);
}

// Round 2
// 87.998 us; speedup vs baseline: 1.1752x; 1.0344x over previous
//
#include <hip/hip_runtime.h>
#include <hip/hip_fp16.h>
#include <math.h>

#define NPTS 17
#define DCH 128
#define HF 56
#define WF 100

using half8 = __attribute__((ext_vector_type(8))) _Float16;
using f32x4 = __attribute__((ext_vector_type(4))) float;

// ---- workspace layout (float offsets) ----
#define OFF_WKB   0          // 128 f32: q_W @ k_b
#define OFF_A0    24576      // 128
#define OFF_B0    24704      // 128
#define OFF_C0    24832      // 1
#define OFF_W2T   24836      // 128*128 f16: w2t[c][k] = sum_e qW[k][e] kW[c][e]
#define OFF_BMT   33028      // 128*128 f16: BmT[d][i] = sum_e vW[i][e] outW[e][d]
#define OFF_FEAT  41220      // 2*56*100*128 f16
#define OFF_LRN   3318020    // 40000*34 f32
#define OFF_IDX   4758020    // 40000 ints (compacted: [valid... | skip...])
#define OFF_CNT   4798020    // 2 ints (memset to 0 each launch)

__device__ inline __half2 bc_h2(unsigned u) { return __builtin_bit_cast(__half2, u); }
__device__ inline unsigned bc_u32(__half2 h) { return __builtin_bit_cast(unsigned, h); }
__device__ inline unsigned packh2(float a, float b) {
  return bc_u32(__float22half2_rn(make_float2(a, b)));
}
__device__ inline ushort f2hu(float x) {
  __half h = __float2half(x);
  return __builtin_bit_cast(ushort, h);
}

__device__ inline int swz(int row, int bcol) {        // 256B rows
  return (row << 8) + (bcol ^ ((row & 7) << 4));
}
__device__ inline int swz7(int row, int bcol) {       // 128B rows
  return (row << 7) + (bcol ^ ((row & 7) << 4));
}

// shared projection: (u_n, v_n) for point n
__device__ inline void project(int4 iv, const float* voxel_size,
    const float* pc_range, const float* trans, float winv, float hinv,
    float& u_n, float& v_n, int& bidx)
{
  bidx = iv.x;
  float cv0 = voxel_size[0]*8.f, cv1 = voxel_size[1]*8.f, cv2 = voxel_size[2]*8.f;
  float ph0 = (float)iv.w*cv0 + pc_range[0] + 0.5f*cv0;
  float ph1 = (float)iv.z*cv1 + pc_range[1] + 0.5f*cv1;
  float ph2 = (float)iv.y*cv2 + pc_range[2] + 0.5f*cv2;
  const float* T = trans + bidx*12;
  float p0 = T[0]*ph0 + T[1]*ph1 + T[2]*ph2  + T[3];
  float p1 = T[4]*ph0 + T[5]*ph1 + T[6]*ph2  + T[7];
  float p2 = T[8]*ph0 + T[9]*ph1 + T[10]*ph2 + T[11];
  float depth = fmaxf(p2, 1e-5f);
  u_n = 2.f*((p0/depth)*winv/99.f) - 1.f;
  v_n = 2.f*((p1/depth)*hinv/55.f) - 1.f;
}

// K1: [0,112) feat | [112,112+nbc) compact | +0 w2t MFMA | +1 bmt MFMA |
//     +2 aux | [+3,+3+rofs) ofs fp32 GEMM (LRN only)
__global__ __launch_bounds__(256) void prep_kernel(
    const float* __restrict__ img,
    const float* __restrict__ q_W, const float* __restrict__ k_W,
    const float* __restrict__ v_W, const float* __restrict__ out_W,
    const float* __restrict__ q_b, const float* __restrict__ k_b,
    const float* __restrict__ v_b,
    const float* __restrict__ offset_W, const float* __restrict__ offset_b,
    const float* __restrict__ X,
    const int* __restrict__ indices,
    const float* __restrict__ voxel_size, const float* __restrict__ pc_range,
    const float* __restrict__ trans,
    const int* __restrict__ HimgP, const int* __restrict__ WimgP,
    float* __restrict__ ws, int N, int nbc)
{
  __shared__ __align__(16) char smraw[51712];
  int tid = threadIdx.x;
  int bid = blockIdx.x;

  if (bid < 112) {
    // ---- img feats -> channel-last f16 ----
    float* sm = (float*)smraw;
    int b = bid / HF, y = bid % HF;
    const float* src = img + (size_t)b*DCH*HF*WF + y*WF;
    #pragma unroll
    for (int i = 0; i < 50; ++i) {
      int flat = i*256 + tid;
      int c = flat / WF;
      int x = flat - c*WF;
      sm[c*101 + x] = src[(size_t)c*HF*WF + x];
    }
    __syncthreads();
    unsigned* dst = (unsigned*)((ushort*)(ws + OFF_FEAT) + (size_t)(b*HF*WF + y*WF)*DCH);
    #pragma unroll
    for (int i = 0; i < 25; ++i) {
      int flat = i*256 + tid;
      int x = flat >> 6;
      int cp = flat & 63;
      dst[(size_t)x*64 + cp] = packh2(sm[(2*cp)*101 + x], sm[(2*cp+1)*101 + x]);
    }
    return;
  }
  bid -= 112;

  if (bid < nbc) {
    // ---- compaction (counters pre-zeroed by memset) ----
    int n = bid * 256 + tid;
    if (n >= N) return;
    const float du = 2.0f/99.0f, dv = 2.0f/55.0f;
    float winv = (float)WF / (float)(WimgP[0]);
    float hinv = (float)HF / (float)(HimgP[0]);
    float u_n, v_n; int bx;
    project(((const int4*)indices)[n], voxel_size, pc_range, trans, winv, hinv,
            u_n, v_n, bx);
    bool cskip = (fabsf(u_n) > 1.001f + 4.5f*du) || (fabsf(v_n) > 1.001f + 4.5f*dv);
    int* cnt = (int*)(ws + OFF_CNT);
    int* idx = (int*)(ws + OFF_IDX);
    if (!cskip) {
      int s = atomicAdd(&cnt[0], 1);
      idx[s] = n;
    } else {
      int s = atomicAdd(&cnt[1], 1);
      idx[N - 1 - s] = n;
    }
    return;
  }
  bid -= nbc;

  if (bid == 0) {
    // ---- w2t[t][j] = sum_e kW[t][e] qW[j][e] ----
    char* Als = smraw;
    char* Bls = smraw + 16384;
    ushort* w2t = (ushort*)(ws + OFF_W2T);
    int wid = tid >> 6, l = tid & 63, lr = l & 15, lg = l >> 4;
    f32x4 acc[2][8] = {};
    for (int ko = 0; ko < 2; ++ko) {
      __syncthreads();
      #pragma unroll
      for (int i = 0; i < 16; ++i) {
        int flat = i*256 + tid;
        int r = flat >> 5, kp = flat & 31;
        float2 va = *(const float2*)&k_W[r*DCH + ko*64 + 2*kp];
        float2 vb = *(const float2*)&q_W[r*DCH + ko*64 + 2*kp];
        *(unsigned*)(Als + swz7(r, kp*4)) = packh2(va.x, va.y);
        *(unsigned*)(Bls + swz7(r, kp*4)) = packh2(vb.x, vb.y);
      }
      __syncthreads();
      #pragma unroll
      for (int kc = 0; kc < 2; ++kc) {
        int kb = kc*64 + lg*16;
        half8 a0 = *(const half8*)(Als + swz7(wid*32 + lr, kb));
        half8 a1 = *(const half8*)(Als + swz7(wid*32 + 16 + lr, kb));
        #pragma unroll
        for (int ni = 0; ni < 8; ++ni) {
          half8 b = *(const half8*)(Bls + swz7(ni*16 + lr, kb));
          acc[0][ni] = __builtin_amdgcn_mfma_f32_16x16x32_f16(a0, b, acc[0][ni], 0, 0, 0);
          acc[1][ni] = __builtin_amdgcn_mfma_f32_16x16x32_f16(a1, b, acc[1][ni], 0, 0, 0);
        }
      }
    }
    #pragma unroll
    for (int mi = 0; mi < 2; ++mi)
      #pragma unroll
      for (int reg = 0; reg < 4; ++reg) {
        int n = wid*32 + mi*16 + lg*4 + reg;
        #pragma unroll
        for (int ni = 0; ni < 8; ++ni)
          w2t[n*DCH + ni*16 + lr] = f2hu(acc[mi][ni][reg]);
      }
    return;
  }
  bid -= 1;

  if (bid == 0) {
    // ---- BmT[d][i] = sum_e vW[i][e] outW[e][d]  (MFMA; A = outW^T) ----
    char* Als = smraw;
    char* Bls = smraw + 16384;
    ushort* bmt = (ushort*)(ws + OFF_BMT);
    int wid = tid >> 6, l = tid & 63, lr = l & 15, lg = l >> 4;
    f32x4 acc[2][8] = {};
    for (int ko = 0; ko < 2; ++ko) {
      __syncthreads();
      // A: Als[d][e'] = outW[(ko*64+e')*128 + d]
      #pragma unroll
      for (int i = 0; i < 32; ++i) {
        int flat = i*256 + tid;          // 8192
        int e = flat >> 7, d = flat & 127;
        float v = out_W[(size_t)(ko*64 + e)*DCH + d];
        *(ushort*)(Als + swz7(d, e*2)) = f2hu(v);
      }
      // B: Bls[i][e'] = vW[i][ko*64+e']
      #pragma unroll
      for (int i = 0; i < 16; ++i) {
        int flat = i*256 + tid;
        int r = flat >> 5, kp = flat & 31;
        float2 vb = *(const float2*)&v_W[r*DCH + ko*64 + 2*kp];
        *(unsigned*)(Bls + swz7(r, kp*4)) = packh2(vb.x, vb.y);
      }
      __syncthreads();
      #pragma unroll
      for (int kc = 0; kc < 2; ++kc) {
        int kb = kc*64 + lg*16;
        half8 a0 = *(const half8*)(Als + swz7(wid*32 + lr, kb));
        half8 a1 = *(const half8*)(Als + swz7(wid*32 + 16 + lr, kb));
        #pragma unroll
        for (int ni = 0; ni < 8; ++ni) {
          half8 b = *(const half8*)(Bls + swz7(ni*16 + lr, kb));
          acc[0][ni] = __builtin_amdgcn_mfma_f32_16x16x32_f16(a0, b, acc[0][ni], 0, 0, 0);
          acc[1][ni] = __builtin_amdgcn_mfma_f32_16x16x32_f16(a1, b, acc[1][ni], 0, 0, 0);
        }
      }
    }
    #pragma unroll
    for (int mi = 0; mi < 2; ++mi)
      #pragma unroll
      for (int reg = 0; reg < 4; ++reg) {
        int d = wid*32 + mi*16 + lg*4 + reg;
        #pragma unroll
        for (int ni = 0; ni < 8; ++ni)
          bmt[d*DCH + ni*16 + lr] = f2hu(acc[mi][ni][reg]);
      }
    return;
  }
  bid -= 1;

  if (bid == 0) {
    // ---- aux: a0 = kW@q_b, wkb = qW@k_b (wave row-reduce); b0 = outW^T@v_b; c0 ----
    int wv = tid >> 6, ln = tid & 63;
    const float* M   = (wv < 2) ? k_W : q_W;
    const float* vec = (wv < 2) ? q_b : k_b;
    int obase = (wv < 2) ? OFF_A0 : OFF_WKB;
    float v0 = vec[ln], v1 = vec[64 + ln];
    int rbase = (wv & 1) * 64;
    for (int r = 0; r < 64; ++r) {
      int row = rbase + r;
      float s = M[(size_t)row*DCH + ln]*v0 + M[(size_t)row*DCH + 64 + ln]*v1;
      s += __shfl_xor(s, 32); s += __shfl_xor(s, 16); s += __shfl_xor(s, 8);
      s += __shfl_xor(s, 4);  s += __shfl_xor(s, 2);  s += __shfl_xor(s, 1);
      if (ln == 0) ws[obase + row] = s;
    }
    if (tid < DCH) {
      float acc = 0.f;
      for (int e = 0; e < DCH; ++e) acc += v_b[e] * out_W[(size_t)e*DCH + tid];
      ws[OFF_B0 + tid] = acc;
    }
    if (wv == 0) {
      float c = q_b[ln]*k_b[ln] + q_b[64+ln]*k_b[64+ln];
      c += __shfl_xor(c, 32); c += __shfl_xor(c, 16); c += __shfl_xor(c, 8);
      c += __shfl_xor(c, 4);  c += __shfl_xor(c, 2);  c += __shfl_xor(c, 1);
      if (ln == 0) ws[OFF_C0] = c;
    }
    return;
  }
  bid -= 1;

  // ---- ofs: fp32 GEMM -> LRN(34) for all rows ----
  {
    int n0 = bid * 64;
    float* XsT = (float*)smraw;              // [64][68]
    float* Ws  = (float*)(smraw + 17408);    // [64][36]
    float acc[4][4] = {};
    int tr = (tid & 15) << 2;
    int tc = (tid >> 4) << 2;
    for (int kc = 0; kc < 2; ++kc) {
      __syncthreads();
      #pragma unroll
      for (int i = 0; i < 16; ++i) {
        int flat = i*256 + tid;
        int r = flat >> 6, k = flat & 63;
        int rr = n0 + r; if (rr >= N) rr = N - 1;
        XsT[k*68 + r] = X[(size_t)rr*DCH + kc*64 + k];
      }
      #pragma unroll
      for (int i = 0; i < 9; ++i) {
        int flat = i*256 + tid;
        if (flat < 2304) {
          int k = flat / 36, c = flat - k*36;
          Ws[k*36 + c] = (c < 34) ? offset_W[(size_t)(kc*64 + k)*34 + c] : 0.f;
        }
      }
      __syncthreads();
      #pragma unroll 8
      for (int k = 0; k < 64; ++k) {
        float4 a = *(const float4*)&XsT[k*68 + tr];
        float4 b = *(const float4*)&Ws[k*36 + tc];
        acc[0][0] += a.x*b.x; acc[0][1] += a.x*b.y; acc[0][2] += a.x*b.z; acc[0][3] += a.x*b.w;
        acc[1][0] += a.y*b.x; acc[1][1] += a.y*b.y; acc[1][2] += a.y*b.z; acc[1][3] += a.y*b.w;
        acc[2][0] += a.z*b.x; acc[2][1] += a.z*b.y; acc[2][2] += a.z*b.z; acc[2][3] += a.z*b.w;
        acc[3][0] += a.w*b.x; acc[3][1] += a.w*b.y; acc[3][2] += a.w*b.z; acc[3][3] += a.w*b.w;
      }
    }
    const float du = 2.0f/99.0f, dv = 2.0f/55.0f;
    #pragma unroll
    for (int i = 0; i < 4; ++i) {
      int n = n0 + tr + i;
      if (n >= N) continue;
      #pragma unroll
      for (int j = 0; j < 4; ++j) {
        int o = tc + j;
        if (o < 34) {
          float sc = (o & 1) ? 1.5f*dv : 1.5f*du;
          ws[OFF_LRN + (size_t)n*34 + o] = tanhf(acc[i][j] + offset_b[o]) * sc;
        }
      }
    }
  }
}

// invalid-point epilogue (stats + out_b row fill), one 16-lane group per point
__device__ inline void fill_point(float* out, const float* out_b,
                                  const float* LRN, int pt, int mm, int N)
{
  const float du = 2.0f/99.0f, dv = 2.0f/55.0f;
  float instab = 0.f;
  #pragma unroll
  for (int p = 0; p < NPTS; ++p) {
    float2 lr = *(const float2*)&LRN[2*p];
    instab += sqrtf(lr.x*lr.x + lr.y*lr.y);
  }
  *(float4*)&out[(size_t)pt*DCH + 8*mm]     = *(const float4*)&out_b[8*mm];
  *(float4*)&out[(size_t)pt*DCH + 8*mm + 4] = *(const float4*)&out_b[8*mm + 4];
  if (mm == 0) {
    out[(size_t)N*128 + pt] = 0.f;
    float osc = 1.5f * sqrtf(du*du + dv*dv);
    float inst = (instab / 17.f) / fmaxf(osc, 1e-6f);
    out[(size_t)N*129 + pt] = fminf(fmaxf(__expf(-inst), 0.f), 1.f);
    float ent = 17.f * 1.3815511e-5f;
    out[(size_t)N*130 + pt] = fminf(fmaxf(1.f - ent / logf(17.f), 0.f), 1.f);
  }
}

// K2: 16 points/block. Heavy blocks: x-gather -> q~ MFMA -> sample/softmax
// -> PRE -> out MFMA. Pure-invalid blocks: out_b fill + stats only.
__global__ __launch_bounds__(256) void fuse_kernel(
    const float* __restrict__ X,
    const int* __restrict__ indices,
    const float* __restrict__ voxel_size, const float* __restrict__ pc_range,
    const float* __restrict__ trans,
    const int* __restrict__ HimgP, const int* __restrict__ WimgP,
    const float* __restrict__ out_b,
    float* __restrict__ ws, float* __restrict__ out, int N)
{
  __shared__ __align__(16) char B_lds[32768];   // w2t, then bmt
  __shared__ __align__(16) char A_lds[4096];    // x f16 (stays for ck)
  __shared__ __align__(16) char Q_lds[4096];    // q~, then PRE
  __shared__ float sa_lds[16];

  int tid  = threadIdx.x;
  int wave = tid >> 6, lane = tid & 63;
  int g = lane >> 4, mm = lane & 15;
  int lr = lane & 15, lg = lane >> 4;
  int n0 = blockIdx.x * 16;
  int nvalid = ((const int*)(ws + OFF_CNT))[0];
  const int* idxp = (const int*)(ws + OFF_IDX);
  int slot = n0 + wave*4 + g;

  if (n0 >= nvalid) {
    // ---- pure fill block (no syncs) ----
    if (slot < N) {
      int pt = idxp[slot];
      fill_point(out, out_b, ws + OFF_LRN + (size_t)pt*34, pt, mm, N);
    }
    return;
  }

  // ================= heavy block =================
  // stage x rows (f16) + w2t
  #pragma unroll
  for (int i = 0; i < 2; ++i) {
    int flat = i*256 + tid;             // 512
    int r = flat >> 5;
    int k = (flat & 31) * 4;
    int sl = n0 + r; if (sl >= nvalid) sl = nvalid - 1;
    int pr = idxp[sl];
    float4 v = *(const float4*)&X[(size_t)pr*DCH + k];
    uint2 pk; pk.x = packh2(v.x, v.y); pk.y = packh2(v.z, v.w);
    *(uint2*)(A_lds + swz(r, k*2)) = pk;
  }
  {
    const ushort* w2t = (const ushort*)(ws + OFF_W2T);
    #pragma unroll
    for (int i = 0; i < 8; ++i) {
      int flat = i*2048 + tid*8;
      int r = flat >> 7, k = flat & 127;
      *(uint4*)(B_lds + swz(r, k*2)) = *(const uint4*)&w2t[(size_t)r*DCH + k];
    }
  }
  __syncthreads();   // sync1: x + w2t staged

  int row = wave*4 + g;
  // ck = x~ . wkb + c0  (per point; f16 x, f32 accum)
  float ck;
  {
    uint4 xr = *(const uint4*)(A_lds + swz(row, 16*mm));
    const float* wk = ws + OFF_WKB + 8*mm;
    __half2 x01 = bc_h2(xr.x), x23 = bc_h2(xr.y), x45 = bc_h2(xr.z), x67 = bc_h2(xr.w);
    float s = __low2float(x01)*wk[0] + __high2float(x01)*wk[1]
            + __low2float(x23)*wk[2] + __high2float(x23)*wk[3]
            + __low2float(x45)*wk[4] + __high2float(x45)*wk[5]
            + __low2float(x67)*wk[6] + __high2float(x67)*wk[7];
    s += __shfl_xor(s, 8); s += __shfl_xor(s, 4);
    s += __shfl_xor(s, 2); s += __shfl_xor(s, 1);
    ck = s + ws[OFF_C0];
  }

  // q~ MFMA: wave covers cols [wave*32, wave*32+32)
  {
    f32x4 qacc[2] = {};
    #pragma unroll
    for (int kc = 0; kc < 4; ++kc) {
      int kb = kc*64 + lg*16;
      half8 a  = *(const half8*)(A_lds + swz(lr, kb));
      half8 b0 = *(const half8*)(B_lds + swz(wave*32 + lr, kb));
      half8 b1 = *(const half8*)(B_lds + swz(wave*32 + 16 + lr, kb));
      qacc[0] = __builtin_amdgcn_mfma_f32_16x16x32_f16(a, b0, qacc[0], 0, 0, 0);
      qacc[1] = __builtin_amdgcn_mfma_f32_16x16x32_f16(a, b1, qacc[1], 0, 0, 0);
    }
    #pragma unroll
    for (int ni = 0; ni < 2; ++ni)
      #pragma unroll
      for (int reg = 0; reg < 4; ++reg) {
        int r = lg*4 + reg;
        int c = wave*32 + ni*16 + lr;
        *(ushort*)(Q_lds + swz(r, c*2)) = f2hu(qacc[ni][reg] + ws[OFF_A0 + c]);
      }
  }
  __syncthreads();   // sync2: q~ ready; w2t dead

  // stage bmt into B_lds (latency overlaps sampling across waves)
  {
    const ushort* bmt = (const ushort*)(ws + OFF_BMT);
    #pragma unroll
    for (int i = 0; i < 8; ++i) {
      int flat = i*2048 + tid*8;
      int r = flat >> 7, k = flat & 127;
      *(uint4*)(B_lds + swz(r, k*2)) = *(const uint4*)&bmt[(size_t)r*DCH + k];
    }
  }

  // ---- sampling / online softmax ----
  const float du = 2.0f/99.0f, dv = 2.0f/55.0f;
  if (slot >= nvalid) {
    // fill group inside the mixed block
    if (mm == 0) sa_lds[row] = 0.f;
    uint4 z; z.x = 0u; z.y = 0u; z.z = 0u; z.w = 0u;
    *(uint4*)(Q_lds + swz(row, 16*mm)) = z;
    if (slot < N) {
      int pt = idxp[slot];
      fill_point(out, out_b, ws + OFF_LRN + (size_t)pt*34, pt, mm, N);
    }
  } else {
    int pt = idxp[slot];
    const float* LRN = ws + OFF_LRN + (size_t)pt*34;
    float winv = (float)WF / (float)(WimgP[0]);
    float hinv = (float)HF / (float)(HimgP[0]);
    float u_n, v_n; int bidx;
    project(((const int4*)indices)[pt], voxel_size, pc_range, trans, winv, hinv,
            u_n, v_n, bidx);

    uint4 qp = *(const uint4*)(Q_lds + swz(row, 16*mm));
    __half2 q01 = bc_h2(qp.x), q23 = bc_h2(qp.y), q45 = bc_h2(qp.z), q67 = bc_h2(qp.w);

    const float BOX[NPTS] = {-1,-1,-1, 0,0,0, 1,1,1, -3,-3,-3, 0,0, 3,3,3};
    const float BOY[NPTS] = {-1, 0, 1,-1,0,1,-1,0,1, -3, 0, 3, -3,3,-3,0,3};
    const float scale = 0.17677669529663689f;  // 32^-0.5
    const char* fb = (const char*)(ws + OFF_FEAT);

    float larr[NPTS];
    unsigned vm = 0;
    float instab = 0.f;
    float m_run = -1e28f, srun = 0.f;
    __half2 pre01 = __float2half2_rn(0.f), pre23 = __float2half2_rn(0.f);
    __half2 pre45 = __float2half2_rn(0.f), pre67 = __float2half2_rn(0.f);
    int fbase = bidx * (HF*WF);
    int moff = mm * 16;

    #pragma unroll
    for (int p = 0; p < NPTS; ++p) {
      float2 lrn = *(const float2*)&LRN[2*p];
      instab += sqrtf(lrn.x*lrn.x + lrn.y*lrn.y);
      float gx = u_n + BOX[p]*du + lrn.x;
      float gy = v_n + BOY[p]*dv + lrn.y;
      bool valid = (fabsf(gx) <= 1.f) && (fabsf(gy) <= 1.f);
      float l = -1e30f;
      if (valid) {
        vm |= (1u << p);
        float px = fmaf(gx, 49.5f, 49.5f);
        float py = fmaf(gy, 27.5f, 27.5f);
        float fpx = floorf(px), fpy = floorf(py);
        float fx = px - fpx, fy = py - fpy;
        int x0 = (int)fpx, y0 = (int)fpy;
        int x1 = min(x0 + 1, WF - 1), y1 = min(y0 + 1, HF - 1);
        float wy0 = 1.f - fy, wx0 = 1.f - fx;
        __half2 h00 = __float2half2_rn(wy0*wx0);
        __half2 h01 = __float2half2_rn(wy0*fx);
        __half2 h10 = __float2half2_rn(fy*wx0);
        __half2 h11 = __float2half2_rn(fy*fx);
        int r0 = (fbase + y0*WF) << 8, r1 = (fbase + y1*WF) << 8;
        uint4 f00 = *(const uint4*)(fb + r0 + (x0 << 8) + moff);
        uint4 f01 = *(const uint4*)(fb + r0 + (x1 << 8) + moff);
        uint4 f10 = *(const uint4*)(fb + r1 + (x0 << 8) + moff);
        uint4 f11 = *(const uint4*)(fb + r1 + (x1 << 8) + moff);
        __half2 s01 = __hfma2(h00, bc_h2(f00.x),
                      __hfma2(h01, bc_h2(f01.x),
                      __hfma2(h10, bc_h2(f10.x),
                      __hmul2(h11, bc_h2(f11.x)))));
        __half2 s23 = __hfma2(h00, bc_h2(f00.y),
                      __hfma2(h01, bc_h2(f01.y),
                      __hfma2(h10, bc_h2(f10.y),
                      __hmul2(h11, bc_h2(f11.y)))));
        __half2 s45 = __hfma2(h00, bc_h2(f00.z),
                      __hfma2(h01, bc_h2(f01.z),
                      __hfma2(h10, bc_h2(f10.z),
                      __hmul2(h11, bc_h2(f11.z)))));
        __half2 s67 = __hfma2(h00, bc_h2(f00.w),
                      __hfma2(h01, bc_h2(f01.w),
                      __hfma2(h10, bc_h2(f10.w),
                      __hmul2(h11, bc_h2(f11.w)))));
        __half2 dh = __hfma2(s01, q01, __hfma2(s23, q23,
                     __hfma2(s45, q45, __hmul2(s67, q67))));
        float part = __low2float(dh) + __high2float(dh);
        part += __shfl_xor(part, 8);
        part += __shfl_xor(part, 4);
        part += __shfl_xor(part, 2);
        part += __shfl_xor(part, 1);
        l = (part + ck) * scale;
        float nm  = fmaxf(m_run, l);
        float esc = __expf(m_run - nm);
        float a   = __expf(l - nm);
        m_run = nm;
        srun = srun*esc + a;
        __half2 esch = __float2half2_rn(esc);
        __half2 ah   = __float2half2_rn(a);
        pre01 = __hfma2(ah, s01, __hmul2(pre01, esch));
        pre23 = __hfma2(ah, s23, __hmul2(pre23, esch));
        pre45 = __hfma2(ah, s45, __hmul2(pre45, esch));
        pre67 = __hfma2(ah, s67, __hmul2(pre67, esch));
      }
      larr[p] = l;
    }

    bool anyv = (vm != 0);
    float offv = anyv ? (m_run + __logf(srun)) : 1e38f;
    float invs = anyv ? 1.f/srun : 0.f;
    __half2 ih = __float2half2_rn(invs);
    pre01 = __hmul2(pre01, ih);
    pre23 = __hmul2(pre23, ih);
    pre45 = __hmul2(pre45, ih);
    pre67 = __hmul2(pre67, ih);

    float ent = 0.f;
    #pragma unroll
    for (int p = 0; p < NPTS; ++p) {
      float d = offv - larr[p];
      float a = __expf(-d);
      ent += (a >= 1e-6f) ? a*d : 1.3815511e-5f;
    }

    uint4 pw;
    pw.x = bc_u32(pre01);
    pw.y = bc_u32(pre23);
    pw.z = bc_u32(pre45);
    pw.w = bc_u32(pre67);
    *(uint4*)(Q_lds + swz(row, 16*mm)) = pw;
    if (mm == 0) {
      sa_lds[row] = anyv ? 1.f : 0.f;
      out[(size_t)N*128 + pt] = (float)__popc(vm) / 17.f;
      float osc = 1.5f * sqrtf(du*du + dv*dv);
      float inst = (instab / 17.f) / fmaxf(osc, 1e-6f);
      out[(size_t)N*129 + pt] = fminf(fmaxf(__expf(-inst), 0.f), 1.f);
      out[(size_t)N*130 + pt] = fminf(fmaxf(1.f - ent / logf(17.f), 0.f), 1.f);
    }
  }
  __syncthreads();   // sync3: PRE + bmt ready

  // ---- out MFMA: out(16x128) = PRE @ Bm ----
  {
    f32x4 oacc[2] = {};
    #pragma unroll
    for (int kc = 0; kc < 4; ++kc) {
      int kb = kc*64 + lg*16;
      half8 a  = *(const half8*)(Q_lds + swz(lr, kb));
      half8 b0 = *(const half8*)(B_lds + swz(wave*32 + lr, kb));
      half8 b1 = *(const half8*)(B_lds + swz(wave*32 + 16 + lr, kb));
      oacc[0] = __builtin_amdgcn_mfma_f32_16x16x32_f16(a, b0, oacc[0], 0, 0, 0);
      oacc[1] = __builtin_amdgcn_mfma_f32_16x16x32_f16(a, b1, oacc[1], 0, 0, 0);
    }
    #pragma unroll
    for (int reg = 0; reg < 4; ++reg) {
      int r = lg*4 + reg;
      int sl2 = n0 + r;
      if (sl2 >= nvalid) continue;
      int p2 = idxp[sl2];
      float sa = sa_lds[r];
      #pragma unroll
      for (int ni = 0; ni < 2; ++ni) {
        int c = wave*32 + ni*16 + lr;
        out[(size_t)p2*DCH + c] = oacc[ni][reg] + sa*ws[OFF_B0 + c] + out_b[c];
      }
    }
  }
}

extern "C" void kernel_launch(void* const* d_in, const int* in_sizes, int n_in,
                              void* d_out, int out_size, void* d_ws, size_t ws_size,
                              hipStream_t stream) {
  const float* x_lidar    = (const float*)d_in[0];
  const int*   indices    = (const int*)  d_in[1];
  const float* img        = (const float*)d_in[2];
  const float* voxel_size = (const float*)d_in[3];
  const float* pc_range   = (const float*)d_in[4];
  const float* trans      = (const float*)d_in[5];
  const float* offset_W   = (const float*)d_in[6];
  const float* offset_b   = (const float*)d_in[7];
  const float* q_W        = (const float*)d_in[8];
  const float* q_b        = (const float*)d_in[9];
  const float* k_W        = (const float*)d_in[10];
  const float* k_b        = (const float*)d_in[11];
  const float* v_W        = (const float*)d_in[12];
  const float* v_b        = (const float*)d_in[13];
  const float* out_W      = (const float*)d_in[14];
  const float* out_b      = (const float*)d_in[15];
  const int*   Himg       = (const int*)  d_in[16];
  const int*   Wimg       = (const int*)  d_in[17];
  float* ws  = (float*)d_ws;
  float* out = (float*)d_out;
  int N = in_sizes[0] / DCH;
  int nbc  = (N + 255) / 256;
  int rofs = (N + 63) / 64;

  hipMemsetAsync(ws + OFF_CNT, 0, 2*sizeof(int), stream);
  hipLaunchKernelGGL(prep_kernel, dim3(112 + nbc + 3 + rofs), dim3(256), 0, stream,
                     img, q_W, k_W, v_W, out_W, q_b, k_b, v_b,
                     offset_W, offset_b, x_lidar,
                     indices, voxel_size, pc_range, trans, Himg, Wimg, ws, N, nbc);
  hipLaunchKernelGGL(fuse_kernel, dim3((N + 15) / 16), dim3(256), 0, stream,
                     x_lidar, indices, voxel_size, pc_range, trans, Himg, Wimg,
                     out_b, ws, out, N);
}

// Round 3
// 67.157 us; speedup vs baseline: 1.5400x; 1.3103x over previous
//
#include <hip/hip_runtime.h>
#include <hip/hip_fp16.h>
#include <math.h>

#define NPTS 17
#define DCH 128
#define HF 56
#define WF 100

using half8 = __attribute__((ext_vector_type(8))) _Float16;
using f32x4 = __attribute__((ext_vector_type(4))) float;

// ---- workspace layout (float offsets) ----
#define OFF_WKB    0          // 128 f32: q_W @ k_b
#define OFF_A0     24576      // 128
#define OFF_B0     24704      // 128
#define OFF_C0     24832      // 1
#define OFF_W2T    24836      // 128*128 f16: w2t[c][k] = sum_e qW[k][e] kW[c][e]
#define OFF_BMT    33028      // 128*128 f16: BmT[d][i] = sum_e vW[i][e] outW[e][d]
#define OFF_FEAT   41220      // 2*56*100*128 f16
#define OFF_LRN    3318020    // 40000*34 f32
#define OFF_INSTAB 4678020    // 40000 f32: sum_p |lrn_p|
#define OFF_IDX    4758020    // 40000 ints (compacted: [valid... | skip...])
#define OFF_CNT    4798020    // 2 ints (memset to 0 each launch)

__device__ inline __half2 bc_h2(unsigned u) { return __builtin_bit_cast(__half2, u); }
__device__ inline unsigned bc_u32(__half2 h) { return __builtin_bit_cast(unsigned, h); }
__device__ inline unsigned packh2(float a, float b) {
  return bc_u32(__float22half2_rn(make_float2(a, b)));
}
__device__ inline ushort f2hu(float x) {
  __half h = __float2half(x);
  return __builtin_bit_cast(ushort, h);
}

__device__ inline int swz(int row, int bcol) {        // 256B rows
  return (row << 8) + (bcol ^ ((row & 7) << 4));
}
__device__ inline int swz7(int row, int bcol) {       // 128B rows
  return (row << 7) + (bcol ^ ((row & 7) << 4));
}

// shared projection: (u_n, v_n) for point n
__device__ inline void project(int4 iv, const float* voxel_size,
    const float* pc_range, const float* trans, float winv, float hinv,
    float& u_n, float& v_n, int& bidx)
{
  bidx = iv.x;
  float cv0 = voxel_size[0]*8.f, cv1 = voxel_size[1]*8.f, cv2 = voxel_size[2]*8.f;
  float ph0 = (float)iv.w*cv0 + pc_range[0] + 0.5f*cv0;
  float ph1 = (float)iv.z*cv1 + pc_range[1] + 0.5f*cv1;
  float ph2 = (float)iv.y*cv2 + pc_range[2] + 0.5f*cv2;
  const float* T = trans + bidx*12;
  float p0 = T[0]*ph0 + T[1]*ph1 + T[2]*ph2  + T[3];
  float p1 = T[4]*ph0 + T[5]*ph1 + T[6]*ph2  + T[7];
  float p2 = T[8]*ph0 + T[9]*ph1 + T[10]*ph2 + T[11];
  float depth = fmaxf(p2, 1e-5f);
  u_n = 2.f*((p0/depth)*winv/99.f) - 1.f;
  v_n = 2.f*((p1/depth)*hinv/55.f) - 1.f;
}

// K1: [0,224) feat (2 ch-halves) | [224,224+nbc) compact | +0 w2t | +1 bmt |
//     +2 aux | [+3,+3+rofs) ofs split-f16 MFMA (LRN + INSTAB)
__global__ __launch_bounds__(256) void prep_kernel(
    const float* __restrict__ img,
    const float* __restrict__ q_W, const float* __restrict__ k_W,
    const float* __restrict__ v_W, const float* __restrict__ out_W,
    const float* __restrict__ q_b, const float* __restrict__ k_b,
    const float* __restrict__ v_b,
    const float* __restrict__ offset_W, const float* __restrict__ offset_b,
    const float* __restrict__ X,
    const int* __restrict__ indices,
    const float* __restrict__ voxel_size, const float* __restrict__ pc_range,
    const float* __restrict__ trans,
    const int* __restrict__ HimgP, const int* __restrict__ WimgP,
    float* __restrict__ ws, int N, int nbc)
{
  __shared__ __align__(16) char smraw[32768];
  int tid = threadIdx.x;
  int bid = blockIdx.x;

  if (bid < 224) {
    // ---- img feats -> channel-last f16, 64 channels per block ----
    float* sm = (float*)smraw;               // [64][101]
    int by = bid >> 1, ch = bid & 1;
    int b = by / HF, y = by % HF;
    const float* src = img + (size_t)b*DCH*HF*WF + (size_t)ch*64*HF*WF + y*WF;
    #pragma unroll
    for (int i = 0; i < 25; ++i) {
      int flat = i*256 + tid;                // 6400
      int c = flat / WF;
      int x = flat - c*WF;
      sm[c*101 + x] = src[(size_t)c*HF*WF + x];
    }
    __syncthreads();
    unsigned* dst = (unsigned*)((ushort*)(ws + OFF_FEAT) + (size_t)(b*HF*WF + y*WF)*DCH);
    #pragma unroll
    for (int i = 0; i < 13; ++i) {
      int flat = i*256 + tid;                // 3200 used
      if (flat < 3200) {
        int x = flat >> 5;
        int cp = flat & 31;
        dst[(size_t)x*64 + ch*32 + cp] = packh2(sm[(2*cp)*101 + x], sm[(2*cp+1)*101 + x]);
      }
    }
    return;
  }
  bid -= 224;

  if (bid < nbc) {
    // ---- compaction, block-aggregated atomics ----
    int* lc = (int*)smraw;                   // [0,1]=counts, [2,3]=bases
    int n = bid * 256 + tid;
    bool in = (n < N);
    bool cskip = true;
    if (in) {
      const float du = 2.0f/99.0f, dv = 2.0f/55.0f;
      float winv = (float)WF / (float)(WimgP[0]);
      float hinv = (float)HF / (float)(HimgP[0]);
      float u_n, v_n; int bx;
      project(((const int4*)indices)[n], voxel_size, pc_range, trans, winv, hinv,
              u_n, v_n, bx);
      cskip = (fabsf(u_n) > 1.001f + 4.5f*du) || (fabsf(v_n) > 1.001f + 4.5f*dv);
    }
    if (tid < 2) lc[tid] = 0;
    __syncthreads();
    int my = 0;
    if (in) my = atomicAdd(&lc[cskip ? 1 : 0], 1);
    __syncthreads();
    if (tid < 2) lc[2 + tid] = atomicAdd(&((int*)(ws + OFF_CNT))[tid], lc[tid]);
    __syncthreads();
    if (in) {
      int* idx = (int*)(ws + OFF_IDX);
      if (!cskip) idx[lc[2] + my] = n;
      else        idx[N - 1 - (lc[3] + my)] = n;
    }
    return;
  }
  bid -= nbc;

  if (bid == 0) {
    // ---- w2t[t][j] = sum_e kW[t][e] qW[j][e] ----
    char* Als = smraw;
    char* Bls = smraw + 16384;
    ushort* w2t = (ushort*)(ws + OFF_W2T);
    int wid = tid >> 6, l = tid & 63, lr = l & 15, lg = l >> 4;
    f32x4 acc[2][8] = {};
    for (int ko = 0; ko < 2; ++ko) {
      __syncthreads();
      #pragma unroll
      for (int i = 0; i < 16; ++i) {
        int flat = i*256 + tid;
        int r = flat >> 5, kp = flat & 31;
        float2 va = *(const float2*)&k_W[r*DCH + ko*64 + 2*kp];
        float2 vb = *(const float2*)&q_W[r*DCH + ko*64 + 2*kp];
        *(unsigned*)(Als + swz7(r, kp*4)) = packh2(va.x, va.y);
        *(unsigned*)(Bls + swz7(r, kp*4)) = packh2(vb.x, vb.y);
      }
      __syncthreads();
      #pragma unroll
      for (int kc = 0; kc < 2; ++kc) {
        int kb = kc*64 + lg*16;
        half8 a0 = *(const half8*)(Als + swz7(wid*32 + lr, kb));
        half8 a1 = *(const half8*)(Als + swz7(wid*32 + 16 + lr, kb));
        #pragma unroll
        for (int ni = 0; ni < 8; ++ni) {
          half8 b = *(const half8*)(Bls + swz7(ni*16 + lr, kb));
          acc[0][ni] = __builtin_amdgcn_mfma_f32_16x16x32_f16(a0, b, acc[0][ni], 0, 0, 0);
          acc[1][ni] = __builtin_amdgcn_mfma_f32_16x16x32_f16(a1, b, acc[1][ni], 0, 0, 0);
        }
      }
    }
    #pragma unroll
    for (int mi = 0; mi < 2; ++mi)
      #pragma unroll
      for (int reg = 0; reg < 4; ++reg) {
        int n = wid*32 + mi*16 + lg*4 + reg;
        #pragma unroll
        for (int ni = 0; ni < 8; ++ni)
          w2t[n*DCH + ni*16 + lr] = f2hu(acc[mi][ni][reg]);
      }
    return;
  }
  bid -= 1;

  if (bid == 0) {
    // ---- BmT[d][i] = sum_e vW[i][e] outW[e][d] ----
    char* Als = smraw;
    char* Bls = smraw + 16384;
    ushort* bmt = (ushort*)(ws + OFF_BMT);
    int wid = tid >> 6, l = tid & 63, lr = l & 15, lg = l >> 4;
    f32x4 acc[2][8] = {};
    for (int ko = 0; ko < 2; ++ko) {
      __syncthreads();
      #pragma unroll
      for (int i = 0; i < 32; ++i) {
        int flat = i*256 + tid;              // 8192
        int e = flat >> 7, d = flat & 127;
        float v = out_W[(size_t)(ko*64 + e)*DCH + d];
        *(ushort*)(Als + swz7(d, e*2)) = f2hu(v);
      }
      #pragma unroll
      for (int i = 0; i < 16; ++i) {
        int flat = i*256 + tid;
        int r = flat >> 5, kp = flat & 31;
        float2 vb = *(const float2*)&v_W[r*DCH + ko*64 + 2*kp];
        *(unsigned*)(Bls + swz7(r, kp*4)) = packh2(vb.x, vb.y);
      }
      __syncthreads();
      #pragma unroll
      for (int kc = 0; kc < 2; ++kc) {
        int kb = kc*64 + lg*16;
        half8 a0 = *(const half8*)(Als + swz7(wid*32 + lr, kb));
        half8 a1 = *(const half8*)(Als + swz7(wid*32 + 16 + lr, kb));
        #pragma unroll
        for (int ni = 0; ni < 8; ++ni) {
          half8 b = *(const half8*)(Bls + swz7(ni*16 + lr, kb));
          acc[0][ni] = __builtin_amdgcn_mfma_f32_16x16x32_f16(a0, b, acc[0][ni], 0, 0, 0);
          acc[1][ni] = __builtin_amdgcn_mfma_f32_16x16x32_f16(a1, b, acc[1][ni], 0, 0, 0);
        }
      }
    }
    #pragma unroll
    for (int mi = 0; mi < 2; ++mi)
      #pragma unroll
      for (int reg = 0; reg < 4; ++reg) {
        int d = wid*32 + mi*16 + lg*4 + reg;
        #pragma unroll
        for (int ni = 0; ni < 8; ++ni)
          bmt[d*DCH + ni*16 + lr] = f2hu(acc[mi][ni][reg]);
      }
    return;
  }
  bid -= 1;

  if (bid == 0) {
    // ---- aux: parallel dots ----
    float* vbs = (float*)smraw;              // q_b[0:128] k_b[128:256] v_b[256:384]
    if (tid < 128) { vbs[tid] = q_b[tid]; vbs[256 + tid] = v_b[tid]; }
    else vbs[tid] = k_b[tid & 127];
    __syncthreads();
    int r = tid & 127;
    const float* M  = (tid < 128) ? k_W : q_W;
    const float* vv = (tid < 128) ? vbs : vbs + 128;
    float acc = 0.f;
    #pragma unroll 8
    for (int e = 0; e < DCH; e += 4) {
      float4 m = *(const float4*)&M[(size_t)r*DCH + e];
      acc += m.x*vv[e] + m.y*vv[e+1] + m.z*vv[e+2] + m.w*vv[e+3];
    }
    ws[((tid < 128) ? OFF_A0 : OFF_WKB) + r] = acc;
    if (tid < 128) {
      float b0 = 0.f;
      #pragma unroll 8
      for (int e = 0; e < DCH; ++e) b0 += vbs[256 + e] * out_W[(size_t)e*DCH + tid];
      ws[OFF_B0 + tid] = b0;
    }
    if (tid < 64) {
      float c = vbs[tid]*vbs[128+tid] + vbs[64+tid]*vbs[192+tid];
      c += __shfl_xor(c, 32); c += __shfl_xor(c, 16); c += __shfl_xor(c, 8);
      c += __shfl_xor(c, 4);  c += __shfl_xor(c, 2);  c += __shfl_xor(c, 1);
      if (tid == 0) ws[OFF_C0] = c;
    }
    return;
  }
  bid -= 1;

  // ---- ofs: split-f16 MFMA -> LRN(34) + INSTAB ----
  {
    int n0 = bid * 64;
    char* Ah = smraw;                        // [64][128B]
    char* Al = smraw + 8192;
    char* Bh = smraw + 16384;                // [48][128B]
    char* Bl = smraw + 22528;
    int w = tid >> 6, l = tid & 63, lr = l & 15, lg = l >> 4;
    f32x4 acc[3] = {};
    for (int kc = 0; kc < 2; ++kc) {
      __syncthreads();
      #pragma unroll
      for (int i = 0; i < 8; ++i) {
        int flat = i*256 + tid;              // 2048 pairs
        int r = flat >> 5, kp = flat & 31;
        int rr = n0 + r; if (rr >= N) rr = N - 1;
        float2 xv = *(const float2*)&X[(size_t)rr*DCH + kc*64 + 2*kp];
        __half hx = __float2half(xv.x), hy = __float2half(xv.y);
        float lx = xv.x - __half2float(hx), ly = xv.y - __half2float(hy);
        *(unsigned*)(Ah + swz7(r, 4*kp)) = bc_u32(__halves2half2(hx, hy));
        *(unsigned*)(Al + swz7(r, 4*kp)) = packh2(lx, ly);
      }
      #pragma unroll
      for (int i = 0; i < 12; ++i) {
        int flat = i*256 + tid;              // 3072
        int kk = flat / 48, c = flat - kk*48;
        float wv = (c < 34) ? offset_W[(size_t)(kc*64 + kk)*34 + c] : 0.f;
        __half hw = __float2half(wv);
        float lw = wv - __half2float(hw);
        *(ushort*)(Bh + swz7(c, 2*kk)) = __builtin_bit_cast(ushort, hw);
        *(ushort*)(Bl + swz7(c, 2*kk)) = f2hu(lw);
      }
      __syncthreads();
      #pragma unroll
      for (int ks = 0; ks < 2; ++ks) {
        int kb = ks*64 + lg*16;
        half8 ah = *(const half8*)(Ah + swz7(w*16 + lr, kb));
        half8 al = *(const half8*)(Al + swz7(w*16 + lr, kb));
        #pragma unroll
        for (int bn = 0; bn < 3; ++bn) {
          half8 bh = *(const half8*)(Bh + swz7(bn*16 + lr, kb));
          half8 bl = *(const half8*)(Bl + swz7(bn*16 + lr, kb));
          acc[bn] = __builtin_amdgcn_mfma_f32_16x16x32_f16(al, bh, acc[bn], 0, 0, 0);
          acc[bn] = __builtin_amdgcn_mfma_f32_16x16x32_f16(ah, bl, acc[bn], 0, 0, 0);
          acc[bn] = __builtin_amdgcn_mfma_f32_16x16x32_f16(ah, bh, acc[bn], 0, 0, 0);
        }
      }
    }
    const float du = 2.0f/99.0f, dv = 2.0f/55.0f;
    #pragma unroll
    for (int reg = 0; reg < 4; ++reg) {
      int n = n0 + w*16 + lg*4 + reg;
      float vals[3];
      #pragma unroll
      for (int bn = 0; bn < 3; ++bn) {
        int o = bn*16 + lr;
        float vsc = 0.f;
        if (o < 34) {
          float sc = (o & 1) ? 1.5f*dv : 1.5f*du;
          vsc = tanhf(acc[bn][reg] + offset_b[o]) * sc;
          if (n < N) ws[OFF_LRN + (size_t)n*34 + o] = vsc;
        }
        vals[bn] = vsc;
      }
      float p0 = __shfl_xor(vals[0], 1);
      float p1 = __shfl_xor(vals[1], 1);
      float p2 = __shfl_xor(vals[2], 1);
      float s = 0.f;
      if ((lr & 1) == 0) {
        s = sqrtf(vals[0]*vals[0] + p0*p0) + sqrtf(vals[1]*vals[1] + p1*p1)
          + sqrtf(vals[2]*vals[2] + p2*p2);
      }
      s += __shfl_xor(s, 2); s += __shfl_xor(s, 4); s += __shfl_xor(s, 8);
      if (lr == 0 && n < N) ws[OFF_INSTAB + n] = s;
    }
  }
}

// invalid-point epilogue (stats + out_b row fill), one 16-lane group per point
__device__ inline void fill_point(float* out, const float* out_b,
                                  float instab, int pt, int mm, int N)
{
  const float du = 2.0f/99.0f, dv = 2.0f/55.0f;
  *(float4*)&out[(size_t)pt*DCH + 8*mm]     = *(const float4*)&out_b[8*mm];
  *(float4*)&out[(size_t)pt*DCH + 8*mm + 4] = *(const float4*)&out_b[8*mm + 4];
  if (mm == 0) {
    out[(size_t)N*128 + pt] = 0.f;
    float osc = 1.5f * sqrtf(du*du + dv*dv);
    float inst = (instab / 17.f) / fmaxf(osc, 1e-6f);
    out[(size_t)N*129 + pt] = fminf(fmaxf(__expf(-inst), 0.f), 1.f);
    float ent = 17.f * 1.3815511e-5f;
    out[(size_t)N*130 + pt] = fminf(fmaxf(1.f - ent / logf(17.f), 0.f), 1.f);
  }
}

// K2: 16 points/block. Heavy blocks: x-gather -> q~ MFMA -> sample/softmax
// -> PRE -> out MFMA. Pure-invalid blocks: out_b fill + stats only.
__global__ __launch_bounds__(256) void fuse_kernel(
    const float* __restrict__ X,
    const int* __restrict__ indices,
    const float* __restrict__ voxel_size, const float* __restrict__ pc_range,
    const float* __restrict__ trans,
    const int* __restrict__ HimgP, const int* __restrict__ WimgP,
    const float* __restrict__ out_b,
    float* __restrict__ ws, float* __restrict__ out, int N)
{
  __shared__ __align__(16) char B_lds[32768];   // w2t, then bmt
  __shared__ __align__(16) char A_lds[4096];    // x f16 (stays for ck)
  __shared__ __align__(16) char Q_lds[4096];    // q~, then PRE
  __shared__ float sa_lds[16];

  int tid  = threadIdx.x;
  int wave = tid >> 6, lane = tid & 63;
  int g = lane >> 4, mm = lane & 15;
  int lr = lane & 15, lg = lane >> 4;
  int n0 = blockIdx.x * 16;
  int nvalid = ((const int*)(ws + OFF_CNT))[0];
  const int* idxp = (const int*)(ws + OFF_IDX);
  int slot = n0 + wave*4 + g;

  if (n0 >= nvalid) {
    // ---- pure fill block (no syncs) ----
    if (slot < N) {
      int pt = idxp[slot];
      fill_point(out, out_b, ws[OFF_INSTAB + pt], pt, mm, N);
    }
    return;
  }

  // ================= heavy block =================
  #pragma unroll
  for (int i = 0; i < 2; ++i) {
    int flat = i*256 + tid;             // 512
    int r = flat >> 5;
    int k = (flat & 31) * 4;
    int sl = n0 + r; if (sl >= nvalid) sl = nvalid - 1;
    int pr = idxp[sl];
    float4 v = *(const float4*)&X[(size_t)pr*DCH + k];
    uint2 pk; pk.x = packh2(v.x, v.y); pk.y = packh2(v.z, v.w);
    *(uint2*)(A_lds + swz(r, k*2)) = pk;
  }
  {
    const ushort* w2t = (const ushort*)(ws + OFF_W2T);
    #pragma unroll
    for (int i = 0; i < 8; ++i) {
      int flat = i*2048 + tid*8;
      int r = flat >> 7, k = flat & 127;
      *(uint4*)(B_lds + swz(r, k*2)) = *(const uint4*)&w2t[(size_t)r*DCH + k];
    }
  }
  __syncthreads();   // sync1: x + w2t staged

  int row = wave*4 + g;
  float ck;
  {
    uint4 xr = *(const uint4*)(A_lds + swz(row, 16*mm));
    const float* wk = ws + OFF_WKB + 8*mm;
    __half2 x01 = bc_h2(xr.x), x23 = bc_h2(xr.y), x45 = bc_h2(xr.z), x67 = bc_h2(xr.w);
    float s = __low2float(x01)*wk[0] + __high2float(x01)*wk[1]
            + __low2float(x23)*wk[2] + __high2float(x23)*wk[3]
            + __low2float(x45)*wk[4] + __high2float(x45)*wk[5]
            + __low2float(x67)*wk[6] + __high2float(x67)*wk[7];
    s += __shfl_xor(s, 8); s += __shfl_xor(s, 4);
    s += __shfl_xor(s, 2); s += __shfl_xor(s, 1);
    ck = s + ws[OFF_C0];
  }

  // q~ MFMA: wave covers cols [wave*32, wave*32+32)
  {
    f32x4 qacc[2] = {};
    #pragma unroll
    for (int kc = 0; kc < 4; ++kc) {
      int kb = kc*64 + lg*16;
      half8 a  = *(const half8*)(A_lds + swz(lr, kb));
      half8 b0 = *(const half8*)(B_lds + swz(wave*32 + lr, kb));
      half8 b1 = *(const half8*)(B_lds + swz(wave*32 + 16 + lr, kb));
      qacc[0] = __builtin_amdgcn_mfma_f32_16x16x32_f16(a, b0, qacc[0], 0, 0, 0);
      qacc[1] = __builtin_amdgcn_mfma_f32_16x16x32_f16(a, b1, qacc[1], 0, 0, 0);
    }
    #pragma unroll
    for (int ni = 0; ni < 2; ++ni)
      #pragma unroll
      for (int reg = 0; reg < 4; ++reg) {
        int r = lg*4 + reg;
        int c = wave*32 + ni*16 + lr;
        *(ushort*)(Q_lds + swz(r, c*2)) = f2hu(qacc[ni][reg] + ws[OFF_A0 + c]);
      }
  }
  __syncthreads();   // sync2: q~ ready; w2t dead

  // stage bmt into B_lds (latency overlaps sampling across waves)
  {
    const ushort* bmt = (const ushort*)(ws + OFF_BMT);
    #pragma unroll
    for (int i = 0; i < 8; ++i) {
      int flat = i*2048 + tid*8;
      int r = flat >> 7, k = flat & 127;
      *(uint4*)(B_lds + swz(r, k*2)) = *(const uint4*)&bmt[(size_t)r*DCH + k];
    }
  }

  // ---- sampling / online softmax ----
  const float du = 2.0f/99.0f, dv = 2.0f/55.0f;
  if (slot >= nvalid) {
    if (mm == 0) sa_lds[row] = 0.f;
    uint4 z; z.x = 0u; z.y = 0u; z.z = 0u; z.w = 0u;
    *(uint4*)(Q_lds + swz(row, 16*mm)) = z;
    if (slot < N) {
      int pt = idxp[slot];
      fill_point(out, out_b, ws[OFF_INSTAB + pt], pt, mm, N);
    }
  } else {
    int pt = idxp[slot];
    const float* LRN = ws + OFF_LRN + (size_t)pt*34;
    float winv = (float)WF / (float)(WimgP[0]);
    float hinv = (float)HF / (float)(HimgP[0]);
    float u_n, v_n; int bidx;
    project(((const int4*)indices)[pt], voxel_size, pc_range, trans, winv, hinv,
            u_n, v_n, bidx);

    uint4 qp = *(const uint4*)(Q_lds + swz(row, 16*mm));
    __half2 q01 = bc_h2(qp.x), q23 = bc_h2(qp.y), q45 = bc_h2(qp.z), q67 = bc_h2(qp.w);

    const float BOX[NPTS] = {-1,-1,-1, 0,0,0, 1,1,1, -3,-3,-3, 0,0, 3,3,3};
    const float BOY[NPTS] = {-1, 0, 1,-1,0,1,-1,0,1, -3, 0, 3, -3,3,-3,0,3};
    const float scale = 0.17677669529663689f;  // 32^-0.5
    const char* fb = (const char*)(ws + OFF_FEAT);

    float larr[NPTS];
    unsigned vm = 0;
    float m_run = -1e28f, srun = 0.f;
    __half2 pre01 = __float2half2_rn(0.f), pre23 = __float2half2_rn(0.f);
    __half2 pre45 = __float2half2_rn(0.f), pre67 = __float2half2_rn(0.f);
    int fbase = bidx * (HF*WF);
    int moff = mm * 16;

    #pragma unroll
    for (int p = 0; p < NPTS; ++p) {
      float2 lrn = *(const float2*)&LRN[2*p];
      float gx = u_n + BOX[p]*du + lrn.x;
      float gy = v_n + BOY[p]*dv + lrn.y;
      bool valid = (fabsf(gx) <= 1.f) && (fabsf(gy) <= 1.f);
      float l = -1e30f;
      if (valid) {
        vm |= (1u << p);
        float px = fmaf(gx, 49.5f, 49.5f);
        float py = fmaf(gy, 27.5f, 27.5f);
        float fpx = floorf(px), fpy = floorf(py);
        float fx = px - fpx, fy = py - fpy;
        int x0 = (int)fpx, y0 = (int)fpy;
        int x1 = min(x0 + 1, WF - 1), y1 = min(y0 + 1, HF - 1);
        float wy0 = 1.f - fy, wx0 = 1.f - fx;
        __half2 h00 = __float2half2_rn(wy0*wx0);
        __half2 h01 = __float2half2_rn(wy0*fx);
        __half2 h10 = __float2half2_rn(fy*wx0);
        __half2 h11 = __float2half2_rn(fy*fx);
        int r0 = (fbase + y0*WF) << 8, r1 = (fbase + y1*WF) << 8;
        uint4 f00 = *(const uint4*)(fb + r0 + (x0 << 8) + moff);
        uint4 f01 = *(const uint4*)(fb + r0 + (x1 << 8) + moff);
        uint4 f10 = *(const uint4*)(fb + r1 + (x0 << 8) + moff);
        uint4 f11 = *(const uint4*)(fb + r1 + (x1 << 8) + moff);
        __half2 s01 = __hfma2(h00, bc_h2(f00.x),
                      __hfma2(h01, bc_h2(f01.x),
                      __hfma2(h10, bc_h2(f10.x),
                      __hmul2(h11, bc_h2(f11.x)))));
        __half2 s23 = __hfma2(h00, bc_h2(f00.y),
                      __hfma2(h01, bc_h2(f01.y),
                      __hfma2(h10, bc_h2(f10.y),
                      __hmul2(h11, bc_h2(f11.y)))));
        __half2 s45 = __hfma2(h00, bc_h2(f00.z),
                      __hfma2(h01, bc_h2(f01.z),
                      __hfma2(h10, bc_h2(f10.z),
                      __hmul2(h11, bc_h2(f11.z)))));
        __half2 s67 = __hfma2(h00, bc_h2(f00.w),
                      __hfma2(h01, bc_h2(f01.w),
                      __hfma2(h10, bc_h2(f10.w),
                      __hmul2(h11, bc_h2(f11.w)))));
        __half2 dh = __hfma2(s01, q01, __hfma2(s23, q23,
                     __hfma2(s45, q45, __hmul2(s67, q67))));
        float part = __low2float(dh) + __high2float(dh);
        part += __shfl_xor(part, 8);
        part += __shfl_xor(part, 4);
        part += __shfl_xor(part, 2);
        part += __shfl_xor(part, 1);
        l = (part + ck) * scale;
        float nm  = fmaxf(m_run, l);
        float esc = __expf(m_run - nm);
        float a   = __expf(l - nm);
        m_run = nm;
        srun = srun*esc + a;
        __half2 esch = __float2half2_rn(esc);
        __half2 ah   = __float2half2_rn(a);
        pre01 = __hfma2(ah, s01, __hmul2(pre01, esch));
        pre23 = __hfma2(ah, s23, __hmul2(pre23, esch));
        pre45 = __hfma2(ah, s45, __hmul2(pre45, esch));
        pre67 = __hfma2(ah, s67, __hmul2(pre67, esch));
      }
      larr[p] = l;
    }

    bool anyv = (vm != 0);
    float offv = anyv ? (m_run + __logf(srun)) : 1e38f;
    float invs = anyv ? 1.f/srun : 0.f;
    __half2 ih = __float2half2_rn(invs);
    pre01 = __hmul2(pre01, ih);
    pre23 = __hmul2(pre23, ih);
    pre45 = __hmul2(pre45, ih);
    pre67 = __hmul2(pre67, ih);

    float ent = 0.f;
    #pragma unroll
    for (int p = 0; p < NPTS; ++p) {
      float d = offv - larr[p];
      float a = __expf(-d);
      ent += (a >= 1e-6f) ? a*d : 1.3815511e-5f;
    }

    uint4 pw;
    pw.x = bc_u32(pre01);
    pw.y = bc_u32(pre23);
    pw.z = bc_u32(pre45);
    pw.w = bc_u32(pre67);
    *(uint4*)(Q_lds + swz(row, 16*mm)) = pw;
    if (mm == 0) {
      sa_lds[row] = anyv ? 1.f : 0.f;
      out[(size_t)N*128 + pt] = (float)__popc(vm) / 17.f;
      float osc = 1.5f * sqrtf(du*du + dv*dv);
      float inst = (ws[OFF_INSTAB + pt] / 17.f) / fmaxf(osc, 1e-6f);
      out[(size_t)N*129 + pt] = fminf(fmaxf(__expf(-inst), 0.f), 1.f);
      out[(size_t)N*130 + pt] = fminf(fmaxf(1.f - ent / logf(17.f), 0.f), 1.f);
    }
  }
  __syncthreads();   // sync3: PRE + bmt ready

  // ---- out MFMA: out(16x128) = PRE @ Bm ----
  {
    f32x4 oacc[2] = {};
    #pragma unroll
    for (int kc = 0; kc < 4; ++kc) {
      int kb = kc*64 + lg*16;
      half8 a  = *(const half8*)(Q_lds + swz(lr, kb));
      half8 b0 = *(const half8*)(B_lds + swz(wave*32 + lr, kb));
      half8 b1 = *(const half8*)(B_lds + swz(wave*32 + 16 + lr, kb));
      oacc[0] = __builtin_amdgcn_mfma_f32_16x16x32_f16(a, b0, oacc[0], 0, 0, 0);
      oacc[1] = __builtin_amdgcn_mfma_f32_16x16x32_f16(a, b1, oacc[1], 0, 0, 0);
    }
    #pragma unroll
    for (int reg = 0; reg < 4; ++reg) {
      int r = lg*4 + reg;
      int sl2 = n0 + r;
      if (sl2 >= nvalid) continue;
      int p2 = idxp[sl2];
      float sa = sa_lds[r];
      #pragma unroll
      for (int ni = 0; ni < 2; ++ni) {
        int c = wave*32 + ni*16 + lr;
        out[(size_t)p2*DCH + c] = oacc[ni][reg] + sa*ws[OFF_B0 + c] + out_b[c];
      }
    }
  }
}

extern "C" void kernel_launch(void* const* d_in, const int* in_sizes, int n_in,
                              void* d_out, int out_size, void* d_ws, size_t ws_size,
                              hipStream_t stream) {
  const float* x_lidar    = (const float*)d_in[0];
  const int*   indices    = (const int*)  d_in[1];
  const float* img        = (const float*)d_in[2];
  const float* voxel_size = (const float*)d_in[3];
  const float* pc_range   = (const float*)d_in[4];
  const float* trans      = (const float*)d_in[5];
  const float* offset_W   = (const float*)d_in[6];
  const float* offset_b   = (const float*)d_in[7];
  const float* q_W        = (const float*)d_in[8];
  const float* q_b        = (const float*)d_in[9];
  const float* k_W        = (const float*)d_in[10];
  const float* k_b        = (const float*)d_in[11];
  const float* v_W        = (const float*)d_in[12];
  const float* v_b        = (const float*)d_in[13];
  const float* out_W      = (const float*)d_in[14];
  const float* out_b      = (const float*)d_in[15];
  const int*   Himg       = (const int*)  d_in[16];
  const int*   Wimg       = (const int*)  d_in[17];
  float* ws  = (float*)d_ws;
  float* out = (float*)d_out;
  int N = in_sizes[0] / DCH;
  int nbc  = (N + 255) / 256;
  int rofs = (N + 63) / 64;

  hipMemsetAsync(ws + OFF_CNT, 0, 2*sizeof(int), stream);
  hipLaunchKernelGGL(prep_kernel, dim3(224 + nbc + 3 + rofs), dim3(256), 0, stream,
                     img, q_W, k_W, v_W, out_W, q_b, k_b, v_b,
                     offset_W, offset_b, x_lidar,
                     indices, voxel_size, pc_range, trans, Himg, Wimg, ws, N, nbc);
  hipLaunchKernelGGL(fuse_kernel, dim3((N + 15) / 16), dim3(256), 0, stream,
                     x_lidar, indices, voxel_size, pc_range, trans, Himg, Wimg,
                     out_b, ws, out, N);
}

// Round 4
// 45.981 us; speedup vs baseline: 2.2492x; 1.4605x over previous
//
#include <hip/hip_runtime.h>
#include <hip/hip_fp16.h>
#include <math.h>

#define NPTS 17
#define DCH 128
#define HF 56
#define WF 100

using half8 = __attribute__((ext_vector_type(8))) _Float16;
using f32x4 = __attribute__((ext_vector_type(4))) float;

// ---- workspace layout (float offsets) ----
#define OFF_WKB    0          // 128 f32: q_W @ k_b
#define OFF_A0     128        // 128
#define OFF_B0     256        // 128
#define OFF_C0     384        // 1
#define OFF_W2T    512        // 128*128 f16 (8192 fl): w2t[c][k]
#define OFF_BMT    8704       // 128*128 f16 (8192 fl): BmT[d][i]
#define OFF_WOFS   16896      // 2*48*128 f16 (6144 fl): woh | wol  [c][k]
#define OFF_FEAT   23040      // 2*56*100*128 f16 (716800 fl)
#define OFF_UVB    739840     // 40000 float4: (u_n, v_n, bidx, 0)
#define OFF_IDX    899840     // 40000 ints (compacted: [valid... | skip...])
#define OFF_CNT    939840     // 2 ints (memset to 0 each launch)

__device__ inline __half2 bc_h2(unsigned u) { return __builtin_bit_cast(__half2, u); }
__device__ inline unsigned bc_u32(__half2 h) { return __builtin_bit_cast(unsigned, h); }
__device__ inline unsigned packh2(float a, float b) {
  return bc_u32(__float22half2_rn(make_float2(a, b)));
}
__device__ inline ushort f2hu(float x) {
  __half h = __float2half(x);
  return __builtin_bit_cast(ushort, h);
}

__device__ inline int swz(int row, int bcol) {        // 256B rows
  return (row << 8) + (bcol ^ ((row & 7) << 4));
}
__device__ inline int swz7(int row, int bcol) {       // 128B rows
  return (row << 7) + (bcol ^ ((row & 7) << 4));
}

// shared projection: (u_n, v_n) for point n
__device__ inline void project(int4 iv, const float* voxel_size,
    const float* pc_range, const float* trans, float winv, float hinv,
    float& u_n, float& v_n, int& bidx)
{
  bidx = iv.x;
  float cv0 = voxel_size[0]*8.f, cv1 = voxel_size[1]*8.f, cv2 = voxel_size[2]*8.f;
  float ph0 = (float)iv.w*cv0 + pc_range[0] + 0.5f*cv0;
  float ph1 = (float)iv.z*cv1 + pc_range[1] + 0.5f*cv1;
  float ph2 = (float)iv.y*cv2 + pc_range[2] + 0.5f*cv2;
  const float* T = trans + bidx*12;
  float p0 = T[0]*ph0 + T[1]*ph1 + T[2]*ph2  + T[3];
  float p1 = T[4]*ph0 + T[5]*ph1 + T[6]*ph2  + T[7];
  float p2 = T[8]*ph0 + T[9]*ph1 + T[10]*ph2 + T[11];
  float depth = fmaxf(p2, 1e-5f);
  u_n = 2.f*((p0/depth)*winv/99.f) - 1.f;
  v_n = 2.f*((p1/depth)*hinv/55.f) - 1.f;
}

// K1: [0,224) feat (2 ch-halves) | [224,224+nbc) compact+uvb | +0 w2t | +1 bmt |
//     +2 aux + wofs transpose/split
__global__ __launch_bounds__(256) void prep_kernel(
    const float* __restrict__ img,
    const float* __restrict__ q_W, const float* __restrict__ k_W,
    const float* __restrict__ v_W, const float* __restrict__ out_W,
    const float* __restrict__ q_b, const float* __restrict__ k_b,
    const float* __restrict__ v_b,
    const float* __restrict__ offset_W,
    const int* __restrict__ indices,
    const float* __restrict__ voxel_size, const float* __restrict__ pc_range,
    const float* __restrict__ trans,
    const int* __restrict__ HimgP, const int* __restrict__ WimgP,
    float* __restrict__ ws, int N, int nbc)
{
  __shared__ __align__(16) char smraw[32768];
  int tid = threadIdx.x;
  int bid = blockIdx.x;

  if (bid < 224) {
    // ---- img feats -> channel-last f16, 64 channels per block ----
    float* sm = (float*)smraw;               // [64][101]
    int by = bid >> 1, ch = bid & 1;
    int b = by / HF, y = by % HF;
    const float* src = img + (size_t)b*DCH*HF*WF + (size_t)ch*64*HF*WF + y*WF;
    #pragma unroll
    for (int i = 0; i < 25; ++i) {
      int flat = i*256 + tid;                // 6400
      int c = flat / WF;
      int x = flat - c*WF;
      sm[c*101 + x] = src[(size_t)c*HF*WF + x];
    }
    __syncthreads();
    unsigned* dst = (unsigned*)((ushort*)(ws + OFF_FEAT) + (size_t)(b*HF*WF + y*WF)*DCH);
    #pragma unroll
    for (int i = 0; i < 13; ++i) {
      int flat = i*256 + tid;                // 3200 used
      if (flat < 3200) {
        int x = flat >> 5;
        int cp = flat & 31;
        dst[(size_t)x*64 + ch*32 + cp] = packh2(sm[(2*cp)*101 + x], sm[(2*cp+1)*101 + x]);
      }
    }
    return;
  }
  bid -= 224;

  if (bid < nbc) {
    // ---- compaction + uvb, block-aggregated atomics ----
    int* lc = (int*)smraw;                   // [0,1]=counts, [2,3]=bases
    int n = bid * 256 + tid;
    bool in = (n < N);
    bool cskip = true;
    if (in) {
      const float du = 2.0f/99.0f, dv = 2.0f/55.0f;
      float winv = (float)WF / (float)(WimgP[0]);
      float hinv = (float)HF / (float)(HimgP[0]);
      float u_n, v_n; int bx;
      project(((const int4*)indices)[n], voxel_size, pc_range, trans, winv, hinv,
              u_n, v_n, bx);
      ((float4*)(ws + OFF_UVB))[n] = make_float4(u_n, v_n, (float)bx, 0.f);
      cskip = (fabsf(u_n) > 1.001f + 4.5f*du) || (fabsf(v_n) > 1.001f + 4.5f*dv);
    }
    if (tid < 2) lc[tid] = 0;
    __syncthreads();
    int my = 0;
    if (in) my = atomicAdd(&lc[cskip ? 1 : 0], 1);
    __syncthreads();
    if (tid < 2) lc[2 + tid] = atomicAdd(&((int*)(ws + OFF_CNT))[tid], lc[tid]);
    __syncthreads();
    if (in) {
      int* idx = (int*)(ws + OFF_IDX);
      if (!cskip) idx[lc[2] + my] = n;
      else        idx[N - 1 - (lc[3] + my)] = n;
    }
    return;
  }
  bid -= nbc;

  if (bid == 0) {
    // ---- w2t[t][j] = sum_e kW[t][e] qW[j][e] ----
    char* Als = smraw;
    char* Bls = smraw + 16384;
    ushort* w2t = (ushort*)(ws + OFF_W2T);
    int wid = tid >> 6, l = tid & 63, lr = l & 15, lg = l >> 4;
    f32x4 acc[2][8] = {};
    for (int ko = 0; ko < 2; ++ko) {
      __syncthreads();
      #pragma unroll
      for (int i = 0; i < 16; ++i) {
        int flat = i*256 + tid;
        int r = flat >> 5, kp = flat & 31;
        float2 va = *(const float2*)&k_W[r*DCH + ko*64 + 2*kp];
        float2 vb = *(const float2*)&q_W[r*DCH + ko*64 + 2*kp];
        *(unsigned*)(Als + swz7(r, kp*4)) = packh2(va.x, va.y);
        *(unsigned*)(Bls + swz7(r, kp*4)) = packh2(vb.x, vb.y);
      }
      __syncthreads();
      #pragma unroll
      for (int kc = 0; kc < 2; ++kc) {
        int kb = kc*64 + lg*16;
        half8 a0 = *(const half8*)(Als + swz7(wid*32 + lr, kb));
        half8 a1 = *(const half8*)(Als + swz7(wid*32 + 16 + lr, kb));
        #pragma unroll
        for (int ni = 0; ni < 8; ++ni) {
          half8 b = *(const half8*)(Bls + swz7(ni*16 + lr, kb));
          acc[0][ni] = __builtin_amdgcn_mfma_f32_16x16x32_f16(a0, b, acc[0][ni], 0, 0, 0);
          acc[1][ni] = __builtin_amdgcn_mfma_f32_16x16x32_f16(a1, b, acc[1][ni], 0, 0, 0);
        }
      }
    }
    #pragma unroll
    for (int mi = 0; mi < 2; ++mi)
      #pragma unroll
      for (int reg = 0; reg < 4; ++reg) {
        int n = wid*32 + mi*16 + lg*4 + reg;
        #pragma unroll
        for (int ni = 0; ni < 8; ++ni)
          w2t[n*DCH + ni*16 + lr] = f2hu(acc[mi][ni][reg]);
      }
    return;
  }
  bid -= 1;

  if (bid == 0) {
    // ---- BmT[d][i] = sum_e vW[i][e] outW[e][d] ----
    char* Als = smraw;
    char* Bls = smraw + 16384;
    ushort* bmt = (ushort*)(ws + OFF_BMT);
    int wid = tid >> 6, l = tid & 63, lr = l & 15, lg = l >> 4;
    f32x4 acc[2][8] = {};
    for (int ko = 0; ko < 2; ++ko) {
      __syncthreads();
      #pragma unroll
      for (int i = 0; i < 32; ++i) {
        int flat = i*256 + tid;              // 8192
        int e = flat >> 7, d = flat & 127;
        float v = out_W[(size_t)(ko*64 + e)*DCH + d];
        *(ushort*)(Als + swz7(d, e*2)) = f2hu(v);
      }
      #pragma unroll
      for (int i = 0; i < 16; ++i) {
        int flat = i*256 + tid;
        int r = flat >> 5, kp = flat & 31;
        float2 vb = *(const float2*)&v_W[r*DCH + ko*64 + 2*kp];
        *(unsigned*)(Bls + swz7(r, kp*4)) = packh2(vb.x, vb.y);
      }
      __syncthreads();
      #pragma unroll
      for (int kc = 0; kc < 2; ++kc) {
        int kb = kc*64 + lg*16;
        half8 a0 = *(const half8*)(Als + swz7(wid*32 + lr, kb));
        half8 a1 = *(const half8*)(Als + swz7(wid*32 + 16 + lr, kb));
        #pragma unroll
        for (int ni = 0; ni < 8; ++ni) {
          half8 b = *(const half8*)(Bls + swz7(ni*16 + lr, kb));
          acc[0][ni] = __builtin_amdgcn_mfma_f32_16x16x32_f16(a0, b, acc[0][ni], 0, 0, 0);
          acc[1][ni] = __builtin_amdgcn_mfma_f32_16x16x32_f16(a1, b, acc[1][ni], 0, 0, 0);
        }
      }
    }
    #pragma unroll
    for (int mi = 0; mi < 2; ++mi)
      #pragma unroll
      for (int reg = 0; reg < 4; ++reg) {
        int d = wid*32 + mi*16 + lg*4 + reg;
        #pragma unroll
        for (int ni = 0; ni < 8; ++ni)
          bmt[d*DCH + ni*16 + lr] = f2hu(acc[mi][ni][reg]);
      }
    return;
  }
  bid -= 1;

  {
    // ---- aux: parallel dots + wofs transpose/split ----
    float* vbs = (float*)smraw;              // q_b[0:128] k_b[128:256] v_b[256:384]
    if (tid < 128) { vbs[tid] = q_b[tid]; vbs[256 + tid] = v_b[tid]; }
    else vbs[tid] = k_b[tid & 127];
    __syncthreads();
    int r = tid & 127;
    const float* M  = (tid < 128) ? k_W : q_W;
    const float* vv = (tid < 128) ? vbs : vbs + 128;
    float acc = 0.f;
    #pragma unroll 8
    for (int e = 0; e < DCH; e += 4) {
      float4 m = *(const float4*)&M[(size_t)r*DCH + e];
      acc += m.x*vv[e] + m.y*vv[e+1] + m.z*vv[e+2] + m.w*vv[e+3];
    }
    ws[((tid < 128) ? OFF_A0 : OFF_WKB) + r] = acc;
    if (tid < 128) {
      float b0 = 0.f;
      #pragma unroll 8
      for (int e = 0; e < DCH; ++e) b0 += vbs[256 + e] * out_W[(size_t)e*DCH + tid];
      ws[OFF_B0 + tid] = b0;
    }
    if (tid < 64) {
      float c = vbs[tid]*vbs[128+tid] + vbs[64+tid]*vbs[192+tid];
      c += __shfl_xor(c, 32); c += __shfl_xor(c, 16); c += __shfl_xor(c, 8);
      c += __shfl_xor(c, 4);  c += __shfl_xor(c, 2);  c += __shfl_xor(c, 1);
      if (tid == 0) ws[OFF_C0] = c;
    }
    // wofs: woh/wol[c][k] = split(offset_W[k][c]), c<48 (zero-pad c>=34)
    ushort* woh = (ushort*)(ws + OFF_WOFS);
    ushort* wol = woh + 48*128;
    #pragma unroll
    for (int i = 0; i < 24; ++i) {
      int flat = i*256 + tid;                // 6144 = 48*128
      int c = flat >> 7, k = flat & 127;
      float wv = (c < 34) ? offset_W[(size_t)k*34 + c] : 0.f;
      __half hw = __float2half(wv);
      woh[flat] = __builtin_bit_cast(ushort, hw);
      wol[flat] = f2hu(wv - __half2float(hw));
    }
  }
}

// invalid-point epilogue (stats + out_b row fill), one 16-lane group per point
__device__ inline void fill_point(float* out, const float* out_b,
                                  float instab, int pt, int mm, int N)
{
  const float du = 2.0f/99.0f, dv = 2.0f/55.0f;
  *(float4*)&out[(size_t)pt*DCH + 8*mm]     = *(const float4*)&out_b[8*mm];
  *(float4*)&out[(size_t)pt*DCH + 8*mm + 4] = *(const float4*)&out_b[8*mm + 4];
  if (mm == 0) {
    out[(size_t)N*128 + pt] = 0.f;
    float osc = 1.5f * sqrtf(du*du + dv*dv);
    float inst = (instab / 17.f) / fmaxf(osc, 1e-6f);
    out[(size_t)N*129 + pt] = fminf(fmaxf(__expf(-inst), 0.f), 1.f);
    float ent = 17.f * 1.3815511e-5f;
    out[(size_t)N*130 + pt] = fminf(fmaxf(1.f - ent / logf(17.f), 0.f), 1.f);
  }
}

// K2: 16 points/block. All blocks: phase A (split-f16 ofs MFMA -> lrn_lds,
// instab). Fill blocks exit; heavy blocks: q~ MFMA -> sample/softmax -> out MFMA.
__global__ __launch_bounds__(256) void fuse_kernel(
    const float* __restrict__ X,
    const float* __restrict__ offset_b,
    const float* __restrict__ out_b,
    float* __restrict__ ws, float* __restrict__ out, int N)
{
  __shared__ __align__(16) char B_lds[32768];   // Bh|Bl -> w2t -> bmt
  __shared__ __align__(16) char A_lds[4096];    // xh f16 (persists; ck + q-MFMA)
  __shared__ __align__(16) char Q_lds[4096];    // xl -> q~ -> PRE
  __shared__ float lrn_lds[16][36];
  __shared__ float sa_lds[16];

  int tid  = threadIdx.x;
  int wave = tid >> 6, lane = tid & 63;
  int g = lane >> 4, mm = lane & 15;
  int lr = lane & 15, lg = lane >> 4;
  int n0 = blockIdx.x * 16;
  int nvalid = ((const int*)(ws + OFF_CNT))[0];
  const int* idxp = (const int*)(ws + OFF_IDX);
  int slot = n0 + wave*4 + g;
  int row  = wave*4 + g;

  // ---- phase A staging: x hi/lo gather + wofs copy ----
  {
    int r  = tid >> 4;
    int k0 = (tid & 15) * 8;
    int sl = n0 + r; if (sl >= N) sl = N - 1;
    int pr = idxp[sl];
    const float* xp = &X[(size_t)pr*DCH + k0];
    float4 v0 = *(const float4*)xp;
    float4 v1 = *(const float4*)(xp + 4);
    __half h0 = __float2half(v0.x), h1 = __float2half(v0.y);
    __half h2 = __float2half(v0.z), h3 = __float2half(v0.w);
    __half h4 = __float2half(v1.x), h5 = __float2half(v1.y);
    __half h6 = __float2half(v1.z), h7 = __float2half(v1.w);
    uint4 hw;
    hw.x = bc_u32(__halves2half2(h0, h1)); hw.y = bc_u32(__halves2half2(h2, h3));
    hw.z = bc_u32(__halves2half2(h4, h5)); hw.w = bc_u32(__halves2half2(h6, h7));
    uint4 lw;
    lw.x = packh2(v0.x - __half2float(h0), v0.y - __half2float(h1));
    lw.y = packh2(v0.z - __half2float(h2), v0.w - __half2float(h3));
    lw.z = packh2(v1.x - __half2float(h4), v1.y - __half2float(h5));
    lw.w = packh2(v1.z - __half2float(h6), v1.w - __half2float(h7));
    *(uint4*)(A_lds + swz(r, k0*2)) = hw;
    *(uint4*)(Q_lds + swz(r, k0*2)) = lw;
  }
  {
    const ushort* woh = (const ushort*)(ws + OFF_WOFS);
    const ushort* wol = woh + 48*128;
    #pragma unroll
    for (int i = 0; i < 3; ++i) {
      int flat = i*256 + tid;                // 768 uint4 per matrix
      int r = flat >> 4, kq = (flat & 15) * 8;
      *(uint4*)(B_lds + swz(r, kq*2))         = *(const uint4*)&woh[r*128 + kq];
      *(uint4*)(B_lds + 12288 + swz(r, kq*2)) = *(const uint4*)&wol[r*128 + kq];
    }
  }
  __syncthreads();   // sync1: xh/xl + Bh/Bl staged

  const float du = 2.0f/99.0f, dv = 2.0f/55.0f;

  // ---- phase A MFMA (waves 0-2) + tanh epilogue -> lrn_lds ----
  if (wave < 3) {
    f32x4 acc = {};
    #pragma unroll
    for (int kc = 0; kc < 4; ++kc) {
      int kb = kc*64 + lg*16;
      half8 ah = *(const half8*)(A_lds + swz(lr, kb));
      half8 al = *(const half8*)(Q_lds + swz(lr, kb));
      half8 bh = *(const half8*)(B_lds + swz(wave*16 + lr, kb));
      half8 bl = *(const half8*)(B_lds + 12288 + swz(wave*16 + lr, kb));
      acc = __builtin_amdgcn_mfma_f32_16x16x32_f16(al, bh, acc, 0, 0, 0);
      acc = __builtin_amdgcn_mfma_f32_16x16x32_f16(ah, bl, acc, 0, 0, 0);
      acc = __builtin_amdgcn_mfma_f32_16x16x32_f16(ah, bh, acc, 0, 0, 0);
    }
    int o = wave*16 + lr;
    if (o < 34) {
      float sc = (o & 1) ? 1.5f*dv : 1.5f*du;
      float ob = offset_b[o];
      #pragma unroll
      for (int reg = 0; reg < 4; ++reg)
        lrn_lds[lg*4 + reg][o] = tanhf(acc[reg] + ob) * sc;
    }
  }

  // ck = x~ . wkb + c0 (per point; f16 x, f32 accum)
  float ck;
  {
    uint4 xr = *(const uint4*)(A_lds + swz(row, 16*mm));
    const float* wk = ws + OFF_WKB + 8*mm;
    __half2 x01 = bc_h2(xr.x), x23 = bc_h2(xr.y), x45 = bc_h2(xr.z), x67 = bc_h2(xr.w);
    float s = __low2float(x01)*wk[0] + __high2float(x01)*wk[1]
            + __low2float(x23)*wk[2] + __high2float(x23)*wk[3]
            + __low2float(x45)*wk[4] + __high2float(x45)*wk[5]
            + __low2float(x67)*wk[6] + __high2float(x67)*wk[7];
    s += __shfl_xor(s, 8); s += __shfl_xor(s, 4);
    s += __shfl_xor(s, 2); s += __shfl_xor(s, 1);
    ck = s + ws[OFF_C0];
  }
  __syncthreads();   // sync2: lrn_lds complete; Bh/Bl dead

  // ---- instab: 16-lane reduce over lrn_lds[row] ----
  float instab;
  {
    float a = lrn_lds[row][2*mm], b = lrn_lds[row][2*mm + 1];
    float s = sqrtf(a*a + b*b);
    if (mm == 0) {
      float a2 = lrn_lds[row][32], b2 = lrn_lds[row][33];
      s += sqrtf(a2*a2 + b2*b2);
    }
    s += __shfl_xor(s, 1); s += __shfl_xor(s, 2);
    s += __shfl_xor(s, 4); s += __shfl_xor(s, 8);
    instab = s;
  }

  if (n0 >= nvalid) {
    // ---- pure fill block ----
    if (slot < N) fill_point(out, out_b, instab, idxp[slot], mm, N);
    return;
  }

  // ---- stage w2t ----
  {
    const ushort* w2t = (const ushort*)(ws + OFF_W2T);
    #pragma unroll
    for (int i = 0; i < 8; ++i) {
      int flat = i*2048 + tid*8;
      int r = flat >> 7, k = flat & 127;
      *(uint4*)(B_lds + swz(r, k*2)) = *(const uint4*)&w2t[(size_t)r*DCH + k];
    }
  }
  __syncthreads();   // sync3: w2t staged

  // ---- q~ MFMA: wave covers cols [wave*32, wave*32+32) ----
  {
    f32x4 qacc[2] = {};
    #pragma unroll
    for (int kc = 0; kc < 4; ++kc) {
      int kb = kc*64 + lg*16;
      half8 a  = *(const half8*)(A_lds + swz(lr, kb));
      half8 b0 = *(const half8*)(B_lds + swz(wave*32 + lr, kb));
      half8 b1 = *(const half8*)(B_lds + swz(wave*32 + 16 + lr, kb));
      qacc[0] = __builtin_amdgcn_mfma_f32_16x16x32_f16(a, b0, qacc[0], 0, 0, 0);
      qacc[1] = __builtin_amdgcn_mfma_f32_16x16x32_f16(a, b1, qacc[1], 0, 0, 0);
    }
    #pragma unroll
    for (int ni = 0; ni < 2; ++ni)
      #pragma unroll
      for (int reg = 0; reg < 4; ++reg) {
        int r = lg*4 + reg;
        int c = wave*32 + ni*16 + lr;
        *(ushort*)(Q_lds + swz(r, c*2)) = f2hu(qacc[ni][reg] + ws[OFF_A0 + c]);
      }
  }
  __syncthreads();   // sync4: q~ ready; w2t dead

  // stage bmt into B_lds (latency overlaps sampling)
  {
    const ushort* bmt = (const ushort*)(ws + OFF_BMT);
    #pragma unroll
    for (int i = 0; i < 8; ++i) {
      int flat = i*2048 + tid*8;
      int r = flat >> 7, k = flat & 127;
      *(uint4*)(B_lds + swz(r, k*2)) = *(const uint4*)&bmt[(size_t)r*DCH + k];
    }
  }

  // ---- sampling / online softmax ----
  if (slot >= nvalid) {
    if (mm == 0) sa_lds[row] = 0.f;
    uint4 z; z.x = 0u; z.y = 0u; z.z = 0u; z.w = 0u;
    *(uint4*)(Q_lds + swz(row, 16*mm)) = z;
    if (slot < N) fill_point(out, out_b, instab, idxp[slot], mm, N);
  } else {
    int pt = idxp[slot];
    float4 uv = ((const float4*)(ws + OFF_UVB))[pt];
    float u_n = uv.x, v_n = uv.y;
    int bidx = (int)uv.z;

    uint4 qp = *(const uint4*)(Q_lds + swz(row, 16*mm));
    __half2 q01 = bc_h2(qp.x), q23 = bc_h2(qp.y), q45 = bc_h2(qp.z), q67 = bc_h2(qp.w);

    const float BOX[NPTS] = {-1,-1,-1, 0,0,0, 1,1,1, -3,-3,-3, 0,0, 3,3,3};
    const float BOY[NPTS] = {-1, 0, 1,-1,0,1,-1,0,1, -3, 0, 3, -3,3,-3,0,3};
    const float scale = 0.17677669529663689f;  // 32^-0.5
    const char* fb = (const char*)(ws + OFF_FEAT);

    float larr[NPTS];
    unsigned vm = 0;
    float m_run = -1e28f, srun = 0.f;
    __half2 pre01 = __float2half2_rn(0.f), pre23 = __float2half2_rn(0.f);
    __half2 pre45 = __float2half2_rn(0.f), pre67 = __float2half2_rn(0.f);
    int fbase = bidx * (HF*WF);
    int moff = mm * 16;

    #pragma unroll
    for (int p = 0; p < NPTS; ++p) {
      float2 lrn = *(const float2*)&lrn_lds[row][2*p];
      float gx = u_n + BOX[p]*du + lrn.x;
      float gy = v_n + BOY[p]*dv + lrn.y;
      bool valid = (fabsf(gx) <= 1.f) && (fabsf(gy) <= 1.f);
      float l = -1e30f;
      if (valid) {
        vm |= (1u << p);
        float px = fmaf(gx, 49.5f, 49.5f);
        float py = fmaf(gy, 27.5f, 27.5f);
        float fpx = floorf(px), fpy = floorf(py);
        float fx = px - fpx, fy = py - fpy;
        int x0 = (int)fpx, y0 = (int)fpy;
        int x1 = min(x0 + 1, WF - 1), y1 = min(y0 + 1, HF - 1);
        float wy0 = 1.f - fy, wx0 = 1.f - fx;
        __half2 h00 = __float2half2_rn(wy0*wx0);
        __half2 h01 = __float2half2_rn(wy0*fx);
        __half2 h10 = __float2half2_rn(fy*wx0);
        __half2 h11 = __float2half2_rn(fy*fx);
        int r0 = (fbase + y0*WF) << 8, r1 = (fbase + y1*WF) << 8;
        uint4 f00 = *(const uint4*)(fb + r0 + (x0 << 8) + moff);
        uint4 f01 = *(const uint4*)(fb + r0 + (x1 << 8) + moff);
        uint4 f10 = *(const uint4*)(fb + r1 + (x0 << 8) + moff);
        uint4 f11 = *(const uint4*)(fb + r1 + (x1 << 8) + moff);
        __half2 s01 = __hfma2(h00, bc_h2(f00.x),
                      __hfma2(h01, bc_h2(f01.x),
                      __hfma2(h10, bc_h2(f10.x),
                      __hmul2(h11, bc_h2(f11.x)))));
        __half2 s23 = __hfma2(h00, bc_h2(f00.y),
                      __hfma2(h01, bc_h2(f01.y),
                      __hfma2(h10, bc_h2(f10.y),
                      __hmul2(h11, bc_h2(f11.y)))));
        __half2 s45 = __hfma2(h00, bc_h2(f00.z),
                      __hfma2(h01, bc_h2(f01.z),
                      __hfma2(h10, bc_h2(f10.z),
                      __hmul2(h11, bc_h2(f11.z)))));
        __half2 s67 = __hfma2(h00, bc_h2(f00.w),
                      __hfma2(h01, bc_h2(f01.w),
                      __hfma2(h10, bc_h2(f10.w),
                      __hmul2(h11, bc_h2(f11.w)))));
        __half2 dh = __hfma2(s01, q01, __hfma2(s23, q23,
                     __hfma2(s45, q45, __hmul2(s67, q67))));
        float part = __low2float(dh) + __high2float(dh);
        part += __shfl_xor(part, 8);
        part += __shfl_xor(part, 4);
        part += __shfl_xor(part, 2);
        part += __shfl_xor(part, 1);
        l = (part + ck) * scale;
        float nm  = fmaxf(m_run, l);
        float esc = __expf(m_run - nm);
        float a   = __expf(l - nm);
        m_run = nm;
        srun = srun*esc + a;
        __half2 esch = __float2half2_rn(esc);
        __half2 ah   = __float2half2_rn(a);
        pre01 = __hfma2(ah, s01, __hmul2(pre01, esch));
        pre23 = __hfma2(ah, s23, __hmul2(pre23, esch));
        pre45 = __hfma2(ah, s45, __hmul2(pre45, esch));
        pre67 = __hfma2(ah, s67, __hmul2(pre67, esch));
      }
      larr[p] = l;
    }

    bool anyv = (vm != 0);
    float offv = anyv ? (m_run + __logf(srun)) : 1e38f;
    float invs = anyv ? 1.f/srun : 0.f;
    __half2 ih = __float2half2_rn(invs);
    pre01 = __hmul2(pre01, ih);
    pre23 = __hmul2(pre23, ih);
    pre45 = __hmul2(pre45, ih);
    pre67 = __hmul2(pre67, ih);

    float ent = 0.f;
    #pragma unroll
    for (int p = 0; p < NPTS; ++p) {
      float d = offv - larr[p];
      float a = __expf(-d);
      ent += (a >= 1e-6f) ? a*d : 1.3815511e-5f;
    }

    uint4 pw;
    pw.x = bc_u32(pre01);
    pw.y = bc_u32(pre23);
    pw.z = bc_u32(pre45);
    pw.w = bc_u32(pre67);
    *(uint4*)(Q_lds + swz(row, 16*mm)) = pw;
    if (mm == 0) {
      sa_lds[row] = anyv ? 1.f : 0.f;
      out[(size_t)N*128 + pt] = (float)__popc(vm) / 17.f;
      float osc = 1.5f * sqrtf(du*du + dv*dv);
      float inst = (instab / 17.f) / fmaxf(osc, 1e-6f);
      out[(size_t)N*129 + pt] = fminf(fmaxf(__expf(-inst), 0.f), 1.f);
      out[(size_t)N*130 + pt] = fminf(fmaxf(1.f - ent / logf(17.f), 0.f), 1.f);
    }
  }
  __syncthreads();   // sync5: PRE + bmt ready

  // ---- out MFMA: out(16x128) = PRE @ Bm ----
  {
    f32x4 oacc[2] = {};
    #pragma unroll
    for (int kc = 0; kc < 4; ++kc) {
      int kb = kc*64 + lg*16;
      half8 a  = *(const half8*)(Q_lds + swz(lr, kb));
      half8 b0 = *(const half8*)(B_lds + swz(wave*32 + lr, kb));
      half8 b1 = *(const half8*)(B_lds + swz(wave*32 + 16 + lr, kb));
      oacc[0] = __builtin_amdgcn_mfma_f32_16x16x32_f16(a, b0, oacc[0], 0, 0, 0);
      oacc[1] = __builtin_amdgcn_mfma_f32_16x16x32_f16(a, b1, oacc[1], 0, 0, 0);
    }
    #pragma unroll
    for (int reg = 0; reg < 4; ++reg) {
      int r = lg*4 + reg;
      int sl2 = n0 + r;
      if (sl2 >= nvalid) continue;
      int p2 = idxp[sl2];
      float sa = sa_lds[r];
      #pragma unroll
      for (int ni = 0; ni < 2; ++ni) {
        int c = wave*32 + ni*16 + lr;
        out[(size_t)p2*DCH + c] = oacc[ni][reg] + sa*ws[OFF_B0 + c] + out_b[c];
      }
    }
  }
}

extern "C" void kernel_launch(void* const* d_in, const int* in_sizes, int n_in,
                              void* d_out, int out_size, void* d_ws, size_t ws_size,
                              hipStream_t stream) {
  const float* x_lidar    = (const float*)d_in[0];
  const int*   indices    = (const int*)  d_in[1];
  const float* img        = (const float*)d_in[2];
  const float* voxel_size = (const float*)d_in[3];
  const float* pc_range   = (const float*)d_in[4];
  const float* trans      = (const float*)d_in[5];
  const float* offset_W   = (const float*)d_in[6];
  const float* offset_b   = (const float*)d_in[7];
  const float* q_W        = (const float*)d_in[8];
  const float* q_b        = (const float*)d_in[9];
  const float* k_W        = (const float*)d_in[10];
  const float* k_b        = (const float*)d_in[11];
  const float* v_W        = (const float*)d_in[12];
  const float* v_b        = (const float*)d_in[13];
  const float* out_W      = (const float*)d_in[14];
  const float* out_b      = (const float*)d_in[15];
  const int*   Himg       = (const int*)  d_in[16];
  const int*   Wimg       = (const int*)  d_in[17];
  float* ws  = (float*)d_ws;
  float* out = (float*)d_out;
  int N = in_sizes[0] / DCH;
  int nbc = (N + 255) / 256;

  hipMemsetAsync(ws + OFF_CNT, 0, 2*sizeof(int), stream);
  hipLaunchKernelGGL(prep_kernel, dim3(224 + nbc + 3), dim3(256), 0, stream,
                     img, q_W, k_W, v_W, out_W, q_b, k_b, v_b,
                     offset_W, indices, voxel_size, pc_range, trans,
                     Himg, Wimg, ws, N, nbc);
  hipLaunchKernelGGL(fuse_kernel, dim3((N + 15) / 16), dim3(256), 0, stream,
                     x_lidar, offset_b, out_b, ws, out, N);
}